// Round 17
// baseline (2083.371 us; speedup 1.0000x reference)
//
#include <hip/hip_runtime.h>
#include <hip/hip_bf16.h>
#include <type_traits>

#define TT 1024
#define DD 768
#define HH 12
#define LL 12
#define VV 50257
#define MROWS 2048   // B*T

typedef __attribute__((ext_vector_type(4))) float f32x4;
typedef __attribute__((ext_vector_type(16))) float f32x16;
typedef __attribute__((ext_vector_type(8))) short bf16x8;

__device__ __forceinline__ short f2bf(float f) {
  __hip_bfloat16 h = __float2bfloat16(f);
  short s;
  __builtin_memcpy(&s, &h, 2);
  return s;
}

__device__ __forceinline__ void gload16(const void* g, void* l) {
  __builtin_amdgcn_global_load_lds(
      (const __attribute__((address_space(1))) unsigned int*)g,
      (__attribute__((address_space(3))) unsigned int*)l, 16, 0, 0);
}

__device__ __forceinline__ float wsum(float v) {
#pragma unroll
  for (int o = 32; o; o >>= 1) v += __shfl_xor(v, o, 64);
  return v;
}

// ---------------- fp32 -> bf16 weight conversion, 5 tensors in one launch ----------------
struct CvtArgs { const float* s[5]; short* d[5]; long n4[5]; };

__global__ __launch_bounds__(256) void cvt5_k(CvtArgs a, long tot)
{
  const long stride = (long)gridDim.x * 256;
  for (long i = (long)blockIdx.x * 256 + threadIdx.x; i < tot; i += stride) {
    long off = i;
    int s = 0;
#pragma unroll
    for (int q = 0; q < 4; ++q) {
      if (off >= a.n4[s]) { off -= a.n4[s]; ++s; }
    }
    const float4 v = ((const float4*)a.s[s])[off];
    short4 h;
    h.x = f2bf(v.x); h.y = f2bf(v.y); h.z = f2bf(v.z); h.w = f2bf(v.w);
    ((short4*)a.d[s])[off] = h;
  }
}

// ---------------- embedding ----------------
__global__ __launch_bounds__(256) void embed_k(const int* __restrict__ idx,
    const float* __restrict__ tok, const float* __restrict__ pos,
    float* __restrict__ x)
{
  int i = blockIdx.x * 256 + threadIdx.x;
  int d = i % DD;
  int bt = i / DD;
  int t = bt & (TT - 1);
  x[i] = tok[(long)idx[bt] * DD + d] + pos[t * DD + d];
}

// ---------------- LayerNorm: 1 wave per row, 4 rows per block ----------------
__global__ __launch_bounds__(256) void ln_k(const float* __restrict__ x,
    const float* __restrict__ g, const float* __restrict__ b,
    short* __restrict__ out)
{
  const int w = threadIdx.x >> 6;
  const int lane = threadIdx.x & 63;
  const int row = blockIdx.x * 4 + w;
  const float* xr = x + (long)row * DD;
  float4 v[3];
  float s = 0.f, s2 = 0.f;
#pragma unroll
  for (int i = 0; i < 3; ++i) {
    v[i] = ((const float4*)xr)[lane + i * 64];
    s  += v[i].x + v[i].y + v[i].z + v[i].w;
    s2 += v[i].x * v[i].x + v[i].y * v[i].y + v[i].z * v[i].z + v[i].w * v[i].w;
  }
  s = wsum(s); s2 = wsum(s2);
  const float mu = s * (1.f / DD);
  const float var = s2 * (1.f / DD) - mu * mu;
  const float rstd = rsqrtf(var + 1e-5f);
#pragma unroll
  for (int i = 0; i < 3; ++i) {
    const int d0 = (lane + i * 64) * 4;
    short4 h;
    h.x = f2bf((v[i].x - mu) * rstd * g[d0 + 0] + b[d0 + 0]);
    h.y = f2bf((v[i].y - mu) * rstd * g[d0 + 1] + b[d0 + 1]);
    h.z = f2bf((v[i].z - mu) * rstd * g[d0 + 2] + b[d0 + 2]);
    h.w = f2bf((v[i].w - mu) * rstd * g[d0 + 3] + b[d0 + 3]);
    ((short4*)(out + (long)row * DD))[lane + i * 64] = h;
  }
}

// ---------------- flash attention, 4-way kv-split, KVBLK=64 ----------------
__global__ __launch_bounds__(256) void flash_k(const short* __restrict__ qkv,
                                               const short* __restrict__ vt,
                                               short* __restrict__ y)
{
  const int qt = (int)gridDim.x - 1 - (int)blockIdx.x;  // longest blocks first
  const int z  = blockIdx.y;
  const int zb = z / HH, zh = z % HH;
  const int w    = threadIdx.x >> 6;
  const int lane = threadIdx.x & 63;
  const int c = lane & 15, g = lane >> 4;

  __shared__ __align__(16) short Pl[4][16][72];
  __shared__ float Ol[4][16][64];
  __shared__ float ml[4][16], ll[4][16];

  const int qbase = qt * 16;
  const long rowQ = (long)(zb * TT + qbase + c) * (3 * DD) + zh * 64;

  bf16x8 qf[2];
  qf[0] = *(const bf16x8*)(qkv + rowQ + g * 8);
  qf[1] = *(const bf16x8*)(qkv + rowQ + 32 + g * 8);

  f32x4 O[4] = {};
  f32x4 mrun, lrun;
#pragma unroll
  for (int r = 0; r < 4; ++r) { mrun[r] = -1e30f; lrun[r] = 0.f; }

  const float CSC = 0.125f * 1.44269504089f;
  const int nt = (qbase + 15) / 64 + 1;

  for (int t = w; t < nt; t += 4) {
    const int k0 = t * 64;
    f32x4 acc[4] = {};
#pragma unroll
    for (int nf = 0; nf < 4; ++nf) {
      const long rowK = (long)(zb * TT + k0 + nf * 16 + c) * (3 * DD) + DD + zh * 64;
      bf16x8 kf0 = *(const bf16x8*)(qkv + rowK + g * 8);
      bf16x8 kf1 = *(const bf16x8*)(qkv + rowK + 32 + g * 8);
      acc[nf] = __builtin_amdgcn_mfma_f32_16x16x32_bf16(qf[0], kf0, acc[nf], 0, 0, 0);
      acc[nf] = __builtin_amdgcn_mfma_f32_16x16x32_bf16(qf[1], kf1, acc[nf], 0, 0, 0);
    }
    f32x4 tv[4];
    const int mask_needed = (k0 + 63 > qbase);
#pragma unroll
    for (int nf = 0; nf < 4; ++nf) {
      const int k_abs = k0 + nf * 16 + c;
#pragma unroll
      for (int r = 0; r < 4; ++r) {
        float val = acc[nf][r] * CSC;
        if (mask_needed && k_abs > qbase + g * 4 + r) val = -1e30f;
        tv[nf][r] = val;
      }
    }
    f32x4 rmax;
#pragma unroll
    for (int r = 0; r < 4; ++r)
      rmax[r] = fmaxf(fmaxf(tv[0][r], tv[1][r]), fmaxf(tv[2][r], tv[3][r]));
#pragma unroll
    for (int off = 1; off < 16; off <<= 1) {
#pragma unroll
      for (int r = 0; r < 4; ++r) rmax[r] = fmaxf(rmax[r], __shfl_xor(rmax[r], off, 64));
    }
    f32x4 mnew, rfac;
#pragma unroll
    for (int r = 0; r < 4; ++r) {
      mnew[r] = fmaxf(mrun[r], rmax[r]);
      rfac[r] = exp2f(mrun[r] - mnew[r]);
      mrun[r] = mnew[r];
    }
    f32x4 e[4], rsum;
#pragma unroll
    for (int r = 0; r < 4; ++r) rsum[r] = 0.f;
#pragma unroll
    for (int nf = 0; nf < 4; ++nf)
#pragma unroll
      for (int r = 0; r < 4; ++r) {
        e[nf][r] = exp2f(tv[nf][r] - mnew[r]);
        rsum[r] += e[nf][r];
      }
#pragma unroll
    for (int off = 1; off < 16; off <<= 1) {
#pragma unroll
      for (int r = 0; r < 4; ++r) rsum[r] += __shfl_xor(rsum[r], off, 64);
    }
#pragma unroll
    for (int r = 0; r < 4; ++r) lrun[r] = lrun[r] * rfac[r] + rsum[r];
#pragma unroll
    for (int nf = 0; nf < 4; ++nf)
#pragma unroll
      for (int r = 0; r < 4; ++r) O[nf][r] *= rfac[r];
#pragma unroll
    for (int nf = 0; nf < 4; ++nf)
#pragma unroll
      for (int r = 0; r < 4; ++r)
        Pl[w][g * 4 + r][nf * 16 + c] = f2bf(e[nf][r]);
    asm volatile("s_waitcnt lgkmcnt(0)" ::: "memory");
    bf16x8 pf[2];
    pf[0] = *(const bf16x8*)&Pl[w][c][g * 8];
    pf[1] = *(const bf16x8*)&Pl[w][c][32 + g * 8];
#pragma unroll
    for (int nf = 0; nf < 4; ++nf) {
      const long vrow = ((long)z * 64 + nf * 16 + c) * TT + k0;
      const bf16x8 vf0 = *(const bf16x8*)(vt + vrow + g * 8);
      const bf16x8 vf1 = *(const bf16x8*)(vt + vrow + 32 + g * 8);
      O[nf] = __builtin_amdgcn_mfma_f32_16x16x32_bf16(pf[0], vf0, O[nf], 0, 0, 0);
      O[nf] = __builtin_amdgcn_mfma_f32_16x16x32_bf16(pf[1], vf1, O[nf], 0, 0, 0);
    }
  }

#pragma unroll
  for (int nf = 0; nf < 4; ++nf)
#pragma unroll
    for (int r = 0; r < 4; ++r)
      Ol[w][g * 4 + r][nf * 16 + c] = O[nf][r];
  if (c == 0) {
#pragma unroll
    for (int r = 0; r < 4; ++r) { ml[w][g * 4 + r] = mrun[r]; ll[w][g * 4 + r] = lrun[r]; }
  }
  __syncthreads();

  for (int e2 = threadIdx.x; e2 < 16 * 64; e2 += 256) {
    const int row = e2 >> 6, d = e2 & 63;
    const float M = fmaxf(fmaxf(ml[0][row], ml[1][row]), fmaxf(ml[2][row], ml[3][row]));
    float L = 0.f, Ov = 0.f;
#pragma unroll
    for (int u = 0; u < 4; ++u) {
      const float f = exp2f(ml[u][row] - M);
      L += ll[u][row] * f;
      Ov += Ol[u][row][d] * f;
    }
    y[(long)(zb * TT + qbase + row) * DD + zh * 64 + d] = f2bf(Ov / L);
  }
}

// ---------------- LM head: 256x256x64, 512 thr / 8 waves, PIPE counted-vmcnt ----------------
__global__ __launch_bounds__(512) void gemm_lm(
    const short* __restrict__ A, const short* __restrict__ Bm,
    float* __restrict__ C, int M, int N, int K, int lda, int ldb, int ldc)
{
  const int l = blockIdx.x;
  const int x = l & 7;
  const int j = l >> 3;
  const int mt = j & 7;
  const int nl = j >> 3;
  const int npan = (N + 255) / 256;
  const int q = npan >> 3, rr = npan & 7;
  const int cnt = q + (x < rr);
  if (nl >= cnt) return;
  const int nstart = x * q + (x < rr ? x : rr);
  const int n0 = (nstart + nl) * 256;
  const int m0 = mt * 256;

  __shared__ __align__(16) short Als[2][256][64];
  __shared__ __align__(16) short Bls[2][256][64];

  const int tid = threadIdx.x;
  const int lane = tid & 63, wid = tid >> 6;
  const int wr = wid >> 2, wc = wid & 3;

  f32x4 acc[8][4] = {};
  const int kAoff = (lane >> 4) * 8;

  const short* ap[4];
  const short* bp[4];
#pragma unroll
  for (int i = 0; i < 4; ++i) {
    const int cc = i * 512 + tid;
    const int r = cc >> 3, kc = cc & 7;
    ap[i] = A + (long)(m0 + r) * lda + ((kc ^ (r & 7)) << 3);
    int gr = n0 + r; gr = (gr < N) ? gr : (N - 1);
    bp[i] = Bm + (long)gr * ldb + ((kc ^ (r & 7)) << 3);
  }
  const int ldsoff = wid * 64 * 16;

  auto stage = [&](int buf) {
#pragma unroll
    for (int i = 0; i < 4; ++i) {
      gload16(ap[i], (char*)&Als[buf][0][0] + i * 8192 + ldsoff);
      ap[i] += 64;
    }
#pragma unroll
    for (int i = 0; i < 4; ++i) {
      gload16(bp[i], (char*)&Bls[buf][0][0] + i * 8192 + ldsoff);
      bp[i] += 64;
    }
  };

  auto compute = [&](int buf) {
#pragma unroll
    for (int kk = 0; kk < 64; kk += 32) {
      const int kc = (kk + kAoff) >> 3;
      bf16x8 bfr[4];
#pragma unroll
      for (int ni = 0; ni < 4; ++ni) {
        const int Rb = wc * 64 + ni * 16 + (lane & 15);
        bfr[ni] = *(const bf16x8*)&Bls[buf][Rb][(kc ^ (Rb & 7)) << 3];
      }
#pragma unroll
      for (int mi = 0; mi < 8; ++mi) {
        const int Ra = wr * 128 + mi * 16 + (lane & 15);
        const bf16x8 af = *(const bf16x8*)&Als[buf][Ra][(kc ^ (Ra & 7)) << 3];
#pragma unroll
        for (int ni = 0; ni < 4; ++ni)
          acc[mi][ni] = __builtin_amdgcn_mfma_f32_16x16x32_bf16(af, bfr[ni], acc[mi][ni], 0, 0, 0);
      }
    }
  };

  const int KT = K / 64;
  stage(0);
  for (int kt = 0; kt < KT; ++kt) {
    const int cur = kt & 1;
    if (kt + 1 < KT) {
      stage(cur ^ 1);
      asm volatile("s_waitcnt vmcnt(8)");
    } else {
      asm volatile("s_waitcnt vmcnt(0)");
    }
    __builtin_amdgcn_sched_barrier(0);
    __builtin_amdgcn_s_barrier();
    __builtin_amdgcn_sched_barrier(0);
    compute(cur);
    asm volatile("" ::: "memory");
    __builtin_amdgcn_s_barrier();
    __builtin_amdgcn_sched_barrier(0);
  }

  const int rq = (lane >> 4) << 2;
  const int cl = lane & 15;
#pragma unroll
  for (int mi = 0; mi < 8; ++mi) {
#pragma unroll
    for (int ni = 0; ni < 4; ++ni) {
      const int cg = n0 + wc * 64 + ni * 16 + cl;
      if (cg >= N) continue;
      const int rbase = m0 + wr * 128 + mi * 16 + rq;
#pragma unroll
      for (int qq = 0; qq < 4; ++qq)
        C[(long)(rbase + qq) * ldc + cg] = acc[mi][ni][qq];
    }
  }
}

// ---------------- NT GEMM: C[m,n] = sum_k A[m,k] * B[n,k]  (+ epilogue) ----------------
// MFS=16: 16x16x32, separate A/B LDS tiles (conflict-free, layer GEMMs).
// MFS=32: 32x32x16 with interleaved A|B LDS rows (fp32-weight LM fallback only).
// PIPE=true -> 2-phase dbuf, counted vmcnt(GPT); PIPE=false -> single-buffer.
// EPI: 0 fp32*scale ; 1 bf16+bias ; 2 fp32 resid+acc+bias ; 3 bf16 gelu ;
//      5 qkv fused: Q/K -> bf16+bias; V -> bf16+bias transposed into vt (via resid arg)
template<int BM, int BN, int BK, int MFS, typename TB, int EPI, bool LMSWZ, bool PIPE>
__global__ __launch_bounds__(256) void gemm_nt(
    const short* __restrict__ A, const TB* __restrict__ Bm,
    const float* __restrict__ bias, const float* __restrict__ resid,
    void* __restrict__ Cout,
    int M, int N, int K, int lda, int ldb, int ldc,
    long aSB, long aSH, long bSB, long bSH, long cSB, long cSH,
    float scale, int causal)
{
  int n0, m0;
  if constexpr (LMSWZ) {
    const int l = blockIdx.x;
    const int x = l & 7;
    const int j = l >> 3;
    const int mt = j & 15;
    const int nl = j >> 4;
    const int npan = (N + BN - 1) / BN;
    const int q = npan >> 3, rr = npan & 7;
    const int cnt = q + (x < rr);
    if (nl >= cnt) return;
    const int nstart = x * q + (x < rr ? x : rr);
    n0 = (nstart + nl) * BN;
    m0 = mt * BM;
  } else {
    n0 = blockIdx.x * BN;
    m0 = blockIdx.y * BM;
  }
  if (causal && n0 >= m0 + BM) return;
  const int z = blockIdx.z;
  const int zb = z / HH, zh = z % HH;
  const short* Ag = A + zb * aSB + zh * aSH + (long)m0 * lda;
  const TB*    Bg = Bm + zb * bSB + zh * bSH;
  const long  cOff = zb * cSB + zh * cSH;

  constexpr int NBUF = PIPE ? 2 : 1;
  static_assert(MFS == 16 || (BM == BN && !PIPE), "ILV path needs BM==BN, single-buffer");
  __shared__ __align__(16) short LDSb[NBUF * (BM + BN) * BK];

  const int tid = threadIdx.x;
  const int lane = tid & 63, wid = tid >> 6;
  constexpr int WTM = BM / 2, WTN = BN / 2;
  constexpr int FM = WTM / 16, FN = WTN / 16;
  constexpr int FM2 = (MFS == 32) ? WTM / 32 : 1;
  constexpr int FN2 = (MFS == 32) ? WTN / 32 : 1;
  constexpr int AM = (MFS == 16) ? FM : FM2;
  constexpr int AN = (MFS == 16) ? FN : FN2;
  const int wr = wid >> 1, wc = wid & 1;

  using accT = typename std::conditional<MFS == 16, f32x4, f32x16>::type;
  accT acc[AM][AN] = {};

  constexpr bool B_IS_F32 = (sizeof(TB) == 4);
  constexpr int CPR = BK / 8;
  constexpr int NCA = BM * CPR;
  constexpr int NCB = BN * CPR;
  constexpr int IA = NCA / 256, IB = NCB / 256;
  constexpr int GPT = IA + IB;
  static_assert(CPR == 8, "swizzle assumes 128B operand rows (BK=64)");
  static_assert(B_IS_F32 || (NCA % 256 == 0 && NCB % 256 == 0), "chunk grid");

  auto aTile = [&](int buf) -> short* { return LDSb + buf * BM * BK; };
  auto bTile = [&](int buf) -> short* { return LDSb + NBUF * BM * BK + buf * BN * BK; };

  auto compute = [&](int buf) {
    if constexpr (MFS == 16) {
      const int kAoff = (lane >> 4) * 8;
      short* Als = aTile(buf);
      short* Bls = bTile(buf);
#pragma unroll
      for (int kk = 0; kk < BK; kk += 32) {
        bf16x8 af[AM], bfr[AN];
#pragma unroll
        for (int mi = 0; mi < AM; ++mi) {
          const int Ra = wr * WTM + mi * 16 + (lane & 15);
          const int kca = (kk + kAoff) >> 3;
          af[mi] = *(const bf16x8*)&Als[Ra * BK + ((kca ^ (Ra & 7)) << 3)];
        }
#pragma unroll
        for (int ni = 0; ni < AN; ++ni) {
          const int Rb = wc * WTN + ni * 16 + (lane & 15);
          const int kcb = (kk + kAoff) >> 3;
          bfr[ni] = *(const bf16x8*)&Bls[Rb * BK + ((kcb ^ (Rb & 7)) << 3)];
        }
#pragma unroll
        for (int mi = 0; mi < AM; ++mi)
#pragma unroll
          for (int ni = 0; ni < AN; ++ni)
            acc[mi][ni] = __builtin_amdgcn_mfma_f32_16x16x32_bf16(af[mi], bfr[ni], acc[mi][ni], 0, 0, 0);
      }
    } else {
#pragma unroll
      for (int kk = 0; kk < BK; kk += 16) {
        const int kc = (kk >> 3) + (lane >> 5);
        bf16x8 af[AM], bfr[AN];
#pragma unroll
        for (int mi = 0; mi < AM; ++mi) {
          const int Ra = wr * WTM + mi * 32 + (lane & 31);
          af[mi] = *(const bf16x8*)&LDSb[Ra * (2 * BK) + ((kc ^ (Ra & 15)) << 3)];
        }
#pragma unroll
        for (int ni = 0; ni < AN; ++ni) {
          const int Rb = wc * WTN + ni * 32 + (lane & 31);
          bfr[ni] = *(const bf16x8*)&LDSb[Rb * (2 * BK) + (((8 + kc) ^ (Rb & 15)) << 3)];
        }
#pragma unroll
        for (int mi = 0; mi < AM; ++mi)
#pragma unroll
          for (int ni = 0; ni < AN; ++ni)
            acc[mi][ni] = __builtin_amdgcn_mfma_f32_32x32x16_bf16(af[mi], bfr[ni], acc[mi][ni], 0, 0, 0);
      }
    }
  };

  if constexpr (!B_IS_F32) {
    const int ldsoff = wid * 64 * 16;
    {
      const short* ap[IA];
      const short* bp[IB];
#pragma unroll
      for (int i = 0; i < IA; ++i) {
        const int cch = i * 256 + tid;
        const int r = cch / CPR, kc = cch % CPR;
        ap[i] = Ag + (long)r * lda + ((kc ^ (r & 7)) << 3);
      }
#pragma unroll
      for (int i = 0; i < IB; ++i) {
        const int cch = i * 256 + tid;
        const int r = cch / CPR, kc = cch % CPR;
        int gr = n0 + r; gr = (gr < N) ? gr : (N - 1);
        bp[i] = (const short*)Bg + (long)gr * ldb + ((kc ^ (r & 7)) << 3);
      }

      auto stage = [&](int buf) {
#pragma unroll
        for (int i = 0; i < IA; ++i) {
          gload16(ap[i], (char*)aTile(buf) + i * 4096 + ldsoff);
          ap[i] += BK;
        }
#pragma unroll
        for (int i = 0; i < IB; ++i) {
          gload16(bp[i], (char*)bTile(buf) + i * 4096 + ldsoff);
          bp[i] += BK;
        }
      };

      if constexpr (PIPE) {
        const int KT = K / BK;
        stage(0);
        for (int kt = 0; kt < KT; ++kt) {
          const int cur = kt & 1;
          if (kt + 1 < KT) {
            stage(cur ^ 1);
            asm volatile("s_waitcnt vmcnt(%0)" :: "i"(GPT));
          } else {
            asm volatile("s_waitcnt vmcnt(0)");
          }
          __builtin_amdgcn_sched_barrier(0);
          __builtin_amdgcn_s_barrier();
          __builtin_amdgcn_sched_barrier(0);
          compute(cur);
          asm volatile("" ::: "memory");
          __builtin_amdgcn_s_barrier();
          __builtin_amdgcn_sched_barrier(0);
        }
      } else {
        const int KT = K / BK;
        for (int kt = 0; kt < KT; ++kt) {
          stage(0);
          __syncthreads();
          compute(0);
          __syncthreads();
        }
      }
    }
  } else {
    for (int k0 = 0; k0 < K; k0 += BK) {
      if constexpr (MFS == 32) {
#pragma unroll
        for (int cc = tid; cc < BM * CPR; cc += 256) {
          int r = cc / CPR, kc = cc % CPR;
          const uint4 v = *(const uint4*)(Ag + (long)r * lda + k0 + kc * 8);
          *(uint4*)&LDSb[r * (2 * BK) + ((kc ^ (r & 15)) << 3)] = v;
        }
#pragma unroll
        for (int cc = tid; cc < BN * (BK / 4); cc += 256) {
          int r = cc / (BK / 4), kc4 = cc % (BK / 4);
          int gr = n0 + r; gr = (gr < N) ? gr : (N - 1);
          const float4 v = *(const float4*)((const float*)Bg + (long)gr * ldb + k0 + kc4 * 4);
          short4 h4;
          h4.x = f2bf(v.x); h4.y = f2bf(v.y); h4.z = f2bf(v.z); h4.w = f2bf(v.w);
          const int co = 8 + (kc4 >> 1);
          *(short4*)&LDSb[r * (2 * BK) + ((co ^ (r & 15)) << 3) + (kc4 & 1) * 4] = h4;
        }
      } else {
        short* Als = aTile(0);
        short* Bls = bTile(0);
#pragma unroll
        for (int cc = tid; cc < BM * CPR; cc += 256) {
          int r = cc / CPR, kc = cc % CPR;
          const uint4 v = *(const uint4*)(Ag + (long)r * lda + k0 + kc * 8);
          *(uint4*)&Als[r * BK + ((kc ^ (r & 7)) << 3)] = v;
        }
#pragma unroll
        for (int cc = tid; cc < BN * (BK / 4); cc += 256) {
          int r = cc / (BK / 4), kc4 = cc % (BK / 4);
          int gr = n0 + r; gr = (gr < N) ? gr : (N - 1);
          const float4 v = *(const float4*)((const float*)Bg + (long)gr * ldb + k0 + kc4 * 4);
          short4 h4;
          h4.x = f2bf(v.x); h4.y = f2bf(v.y); h4.z = f2bf(v.z); h4.w = f2bf(v.w);
          const int co = kc4 >> 1;
          *(short4*)&Bls[r * BK + ((co ^ (r & 7)) << 3) + (kc4 & 1) * 4] = h4;
        }
      }
      __syncthreads();
      compute(0);
      __syncthreads();
    }
  }

  // ---- epilogue ----
  if constexpr (MFS == 16) {
    const int rq = (lane >> 4) << 2;
    const int cl = lane & 15;
#pragma unroll
    for (int mi = 0; mi < AM; ++mi) {
#pragma unroll
      for (int ni = 0; ni < AN; ++ni) {
        const int cg = n0 + wc * WTN + ni * 16 + cl;
        if (cg >= N) continue;
        const int rbase = m0 + wr * WTM + mi * 16 + rq;
        if constexpr (EPI == 5) {
          if (cg >= 2 * DD) {
            const int hh = (cg - 2 * DD) >> 6, dd2 = (cg - 2 * DD) & 63;
            const int bI = rbase >> 10, tI = rbase & (TT - 1);
            const float bv = bias[cg];
            short4 h4;
            h4.x = f2bf(acc[mi][ni][0] + bv);
            h4.y = f2bf(acc[mi][ni][1] + bv);
            h4.z = f2bf(acc[mi][ni][2] + bv);
            h4.w = f2bf(acc[mi][ni][3] + bv);
            short* vtp = (short*)(void*)resid;
            *(short4*)(vtp + (((long)(bI * HH + hh) * 64 + dd2) << 10) + tI) = h4;
          } else {
#pragma unroll
            for (int q = 0; q < 4; ++q)
              ((short*)Cout)[(long)(rbase + q) * ldc + cg] = f2bf(acc[mi][ni][q] + bias[cg]);
          }
          continue;
        }
#pragma unroll
        for (int q = 0; q < 4; ++q) {
          const long cidx = cOff + (long)(rbase + q) * ldc + cg;
          const float v = acc[mi][ni][q];
          if constexpr (EPI == 0) {
            ((float*)Cout)[cidx] = v * scale;
          } else if constexpr (EPI == 1) {
            ((short*)Cout)[cidx] = f2bf(v + bias[cg]);
          } else if constexpr (EPI == 2) {
            ((float*)Cout)[cidx] = resid[cidx] + v + bias[cg];
          } else if constexpr (EPI == 3) {
            const float zz = v + bias[cg];
            ((short*)Cout)[cidx] = f2bf(0.5f * zz * (1.f + erff(zz * 0.70710678118f)));
          } else {
            ((short*)Cout)[cidx] = f2bf(v);
          }
        }
      }
    }
  } else {
    const int cl = lane & 31;
    const int rhi = (lane >> 5) * 4;
#pragma unroll
    for (int mi = 0; mi < AM; ++mi) {
#pragma unroll
      for (int ni = 0; ni < AN; ++ni) {
        const int cg = n0 + wc * WTN + ni * 32 + cl;
        if (cg >= N) continue;
#pragma unroll
        for (int reg = 0; reg < 16; ++reg) {
          const int row = m0 + wr * WTM + mi * 32 + (reg & 3) + ((reg >> 2) * 8) + rhi;
          const long cidx = cOff + (long)row * ldc + cg;
          const float v = acc[mi][ni][reg];
          if constexpr (EPI == 0) {
            ((float*)Cout)[cidx] = v * scale;
          } else if constexpr (EPI == 1) {
            ((short*)Cout)[cidx] = f2bf(v + bias[cg]);
          } else if constexpr (EPI == 2) {
            ((float*)Cout)[cidx] = resid[cidx] + v + bias[cg];
          } else if constexpr (EPI == 3) {
            const float zz = v + bias[cg];
            ((short*)Cout)[cidx] = f2bf(0.5f * zz * (1.f + erff(zz * 0.70710678118f)));
          } else {
            ((short*)Cout)[cidx] = f2bf(v);
          }
        }
      }
    }
  }
}

// ---------------- model driver ----------------
template<typename TB>
static void run_model(const int* idx, const float* tok_f, const float* pos,
                      const TB* wqkv, const float* bqkv, const TB* wproj, const float* bproj,
                      const float* ln1g, const float* ln1b, const float* ln2g, const float* ln2b,
                      const TB* w1, const float* b1, const TB* w2, const float* b2,
                      const float* lnfg, const float* lnfb, const TB* tok_w,
                      float* xa, float* xb, short* hbf, short* qkv, short* vt,
                      short* ybf, short* ffb,
                      float* out, hipStream_t stream)
{
  embed_k<<<dim3(MROWS * DD / 256), 256, 0, stream>>>(idx, tok_f, pos, xa);

  float* xc = xa;
  float* xn = xb;
  for (int l = 0; l < LL; ++l) {
    ln_k<<<dim3(MROWS / 4), 256, 0, stream>>>(xc, ln1g + l * DD, ln1b + l * DD, hbf);
    // qkv: 64x64 -> 36x32 = 1152 blocks (r17 TLP lever)
    gemm_nt<64, 64, 64, 16, TB, 5, false, true><<<dim3(36, 32, 1), 256, 0, stream>>>(
        hbf, wqkv + (long)l * 3 * DD * DD, bqkv + l * 3 * DD, (const float*)vt, qkv,
        MROWS, 3 * DD, DD, DD, DD, 3 * DD, 0, 0, 0, 0, 0, 0, 1.f, 0);
    flash_k<<<dim3(64, 24), 256, 0, stream>>>(qkv, vt, ybf);
    // proj: 32x64 -> 12x64 = 768 blocks
    gemm_nt<32, 64, 64, 16, TB, 2, false, true><<<dim3(12, 64, 1), 256, 0, stream>>>(
        ybf, wproj + (long)l * DD * DD, bproj + l * DD, xc, xn,
        MROWS, DD, DD, DD, DD, DD, 0, 0, 0, 0, 0, 0, 1.f, 0);
    ln_k<<<dim3(MROWS / 4), 256, 0, stream>>>(xn, ln2g + l * DD, ln2b + l * DD, hbf);
    // fc1: 64x64 -> 48x32 = 1536 blocks
    gemm_nt<64, 64, 64, 16, TB, 3, false, true><<<dim3(48, 32, 1), 256, 0, stream>>>(
        hbf, w1 + (long)l * 4 * DD * DD, b1 + l * 4 * DD, nullptr, ffb,
        MROWS, 4 * DD, DD, DD, DD, 4 * DD, 0, 0, 0, 0, 0, 0, 1.f, 0);
    // fc2: 32x64 -> 768 blocks
    gemm_nt<32, 64, 64, 16, TB, 2, false, true><<<dim3(12, 64, 1), 256, 0, stream>>>(
        ffb, w2 + (long)l * DD * 4 * DD, b2 + l * DD, xn, xc,
        MROWS, DD, 4 * DD, 4 * DD, 4 * DD, DD, 0, 0, 0, 0, 0, 0, 1.f, 0);
  }
  ln_k<<<dim3(MROWS / 4), 256, 0, stream>>>(xc, lnfg, lnfb, hbf);
  if constexpr (sizeof(TB) == 2) {
    gemm_lm<<<dim3(1600, 1, 1), 512, 0, stream>>>(
        hbf, (const short*)tok_w, out, MROWS, VV, DD, DD, DD, VV);
  } else {
    gemm_nt<128, 128, 64, 32, TB, 0, true, false><<<dim3(6400, 1, 1), 256, 0, stream>>>(
        hbf, tok_w, nullptr, nullptr, out,
        MROWS, VV, DD, DD, DD, VV, 0, 0, 0, 0, 0, 0, 1.f, 0);
  }
}

extern "C" void kernel_launch(void* const* d_in, const int* in_sizes, int n_in,
                              void* d_out, int out_size, void* d_ws, size_t ws_size,
                              hipStream_t stream)
{
  const int*   idx  = (const int*)d_in[0];
  const float* tok  = (const float*)d_in[1];
  const float* pos  = (const float*)d_in[2];
  const float* wqkv = (const float*)d_in[3];
  const float* bqkv = (const float*)d_in[4];
  const float* wproj= (const float*)d_in[5];
  const float* bproj= (const float*)d_in[6];
  const float* ln1g = (const float*)d_in[7];
  const float* ln1b = (const float*)d_in[8];
  const float* ln2g = (const float*)d_in[9];
  const float* ln2b = (const float*)d_in[10];
  const float* w1   = (const float*)d_in[11];
  const float* b1   = (const float*)d_in[12];
  const float* w2   = (const float*)d_in[13];
  const float* b2   = (const float*)d_in[14];
  const float* lnfg = (const float*)d_in[15];
  const float* lnfb = (const float*)d_in[16];
  float* out = (float*)d_out;

  const long E_WQKV = (long)LL * 3 * DD * DD;
  const long E_WPRJ = (long)LL * DD * DD;
  const long E_W1   = (long)LL * 4 * DD * DD;
  const long E_W2   = E_W1;
  const long E_TOK  = (long)VV * DD;
  const long E_WSUM = E_WQKV + E_WPRJ + E_W1 + E_W2 + E_TOK;

  const size_t NEED_B = 44040192;
  const size_t NEED_A = NEED_B + 2 * (size_t)E_WSUM;

  if (ws_size < NEED_B) return;
  const bool bf16w = (ws_size >= NEED_A);

  char* ws = (char*)d_ws;
  short *wqkv_h = nullptr, *wprj_h = nullptr, *w1_h = nullptr, *w2_h = nullptr, *tok_h = nullptr;
  if (bf16w) {
    wqkv_h = (short*)ws; ws += E_WQKV * 2;
    wprj_h = (short*)ws; ws += E_WPRJ * 2;
    w1_h   = (short*)ws; ws += E_W1 * 2;
    w2_h   = (short*)ws; ws += E_W2 * 2;
    tok_h  = (short*)ws; ws += E_TOK * 2;
  }
  float* xa  = (float*)ws; ws += (size_t)MROWS * DD * 4;
  float* xb  = (float*)ws; ws += (size_t)MROWS * DD * 4;
  short* hbf = (short*)ws; ws += (size_t)MROWS * DD * 2;
  short* qkv = (short*)ws; ws += (size_t)MROWS * 3 * DD * 2;
  short* vt  = (short*)ws; ws += (size_t)24 * 64 * TT * 2;
  short* ybf = (short*)ws; ws += (size_t)MROWS * DD * 2;
  short* ffb = (short*)ws; ws += (size_t)MROWS * 4 * DD * 2;

  if (bf16w) {
    CvtArgs ca;
    ca.s[0] = wqkv; ca.d[0] = wqkv_h; ca.n4[0] = E_WQKV / 4;
    ca.s[1] = wproj; ca.d[1] = wprj_h; ca.n4[1] = E_WPRJ / 4;
    ca.s[2] = w1;   ca.d[2] = w1_h;   ca.n4[2] = E_W1 / 4;
    ca.s[3] = w2;   ca.d[3] = w2_h;   ca.n4[3] = E_W2 / 4;
    ca.s[4] = tok;  ca.d[4] = tok_h;  ca.n4[4] = E_TOK / 4;
    const long tot = (E_WQKV + E_WPRJ + E_W1 + E_W2 + E_TOK) / 4;
    cvt5_k<<<dim3(4096), 256, 0, stream>>>(ca, tot);
    run_model<short>(idx, tok, pos, wqkv_h, bqkv, wprj_h, bproj,
                     ln1g, ln1b, ln2g, ln2b, w1_h, b1, w2_h, b2, lnfg, lnfb, tok_h,
                     xa, xb, hbf, qkv, vt, ybf, ffb, out, stream);
  } else {
    run_model<float>(idx, tok, pos, wqkv, bqkv, wproj, bproj,
                     ln1g, ln1b, ln2g, ln2b, w1, b1, w2, b2, lnfg, lnfb, tok,
                     xa, xb, hbf, qkv, vt, ybf, ffb, out, stream);
  }
}

// Round 18
// 2032.622 us; speedup vs baseline: 1.0250x; 1.0250x over previous
//
#include <hip/hip_runtime.h>
#include <hip/hip_bf16.h>
#include <type_traits>

#define TT 1024
#define DD 768
#define HH 12
#define LL 12
#define VV 50257
#define MROWS 2048   // B*T

typedef __attribute__((ext_vector_type(4))) float f32x4;
typedef __attribute__((ext_vector_type(16))) float f32x16;
typedef __attribute__((ext_vector_type(8))) short bf16x8;

__device__ __forceinline__ short f2bf(float f) {
  __hip_bfloat16 h = __float2bfloat16(f);
  short s;
  __builtin_memcpy(&s, &h, 2);
  return s;
}

__device__ __forceinline__ void gload16(const void* g, void* l) {
  __builtin_amdgcn_global_load_lds(
      (const __attribute__((address_space(1))) unsigned int*)g,
      (__attribute__((address_space(3))) unsigned int*)l, 16, 0, 0);
}

__device__ __forceinline__ float wsum(float v) {
#pragma unroll
  for (int o = 32; o; o >>= 1) v += __shfl_xor(v, o, 64);
  return v;
}

// ---------------- fp32 -> bf16 weight conversion, 5 tensors in one launch ----------------
struct CvtArgs { const float* s[5]; short* d[5]; long n4[5]; };

__global__ __launch_bounds__(256) void cvt5_k(CvtArgs a, long tot)
{
  const long stride = (long)gridDim.x * 256;
  for (long i = (long)blockIdx.x * 256 + threadIdx.x; i < tot; i += stride) {
    long off = i;
    int s = 0;
#pragma unroll
    for (int q = 0; q < 4; ++q) {
      if (off >= a.n4[s]) { off -= a.n4[s]; ++s; }
    }
    const float4 v = ((const float4*)a.s[s])[off];
    short4 h;
    h.x = f2bf(v.x); h.y = f2bf(v.y); h.z = f2bf(v.z); h.w = f2bf(v.w);
    ((short4*)a.d[s])[off] = h;
  }
}

// ---------------- embedding ----------------
__global__ __launch_bounds__(256) void embed_k(const int* __restrict__ idx,
    const float* __restrict__ tok, const float* __restrict__ pos,
    float* __restrict__ x)
{
  int i = blockIdx.x * 256 + threadIdx.x;
  int d = i % DD;
  int bt = i / DD;
  int t = bt & (TT - 1);
  x[i] = tok[(long)idx[bt] * DD + d] + pos[t * DD + d];
}

// ---------------- LayerNorm: 1 wave per row, 4 rows per block ----------------
__global__ __launch_bounds__(256) void ln_k(const float* __restrict__ x,
    const float* __restrict__ g, const float* __restrict__ b,
    short* __restrict__ out)
{
  const int w = threadIdx.x >> 6;
  const int lane = threadIdx.x & 63;
  const int row = blockIdx.x * 4 + w;
  const float* xr = x + (long)row * DD;
  float4 v[3];
  float s = 0.f, s2 = 0.f;
#pragma unroll
  for (int i = 0; i < 3; ++i) {
    v[i] = ((const float4*)xr)[lane + i * 64];
    s  += v[i].x + v[i].y + v[i].z + v[i].w;
    s2 += v[i].x * v[i].x + v[i].y * v[i].y + v[i].z * v[i].z + v[i].w * v[i].w;
  }
  s = wsum(s); s2 = wsum(s2);
  const float mu = s * (1.f / DD);
  const float var = s2 * (1.f / DD) - mu * mu;
  const float rstd = rsqrtf(var + 1e-5f);
#pragma unroll
  for (int i = 0; i < 3; ++i) {
    const int d0 = (lane + i * 64) * 4;
    short4 h;
    h.x = f2bf((v[i].x - mu) * rstd * g[d0 + 0] + b[d0 + 0]);
    h.y = f2bf((v[i].y - mu) * rstd * g[d0 + 1] + b[d0 + 1]);
    h.z = f2bf((v[i].z - mu) * rstd * g[d0 + 2] + b[d0 + 2]);
    h.w = f2bf((v[i].w - mu) * rstd * g[d0 + 3] + b[d0 + 3]);
    ((short4*)(out + (long)row * DD))[lane + i * 64] = h;
  }
}

// ---------------- flash attention, 4-way kv-split, KVBLK=64, T5 setprio ----------------
__global__ __launch_bounds__(256) void flash_k(const short* __restrict__ qkv,
                                               const short* __restrict__ vt,
                                               short* __restrict__ y)
{
  const int qt = (int)gridDim.x - 1 - (int)blockIdx.x;  // longest blocks first
  const int z  = blockIdx.y;
  const int zb = z / HH, zh = z % HH;
  const int w    = threadIdx.x >> 6;
  const int lane = threadIdx.x & 63;
  const int c = lane & 15, g = lane >> 4;

  __shared__ __align__(16) short Pl[4][16][72];
  __shared__ float Ol[4][16][64];
  __shared__ float ml[4][16], ll[4][16];

  const int qbase = qt * 16;
  const long rowQ = (long)(zb * TT + qbase + c) * (3 * DD) + zh * 64;

  bf16x8 qf[2];
  qf[0] = *(const bf16x8*)(qkv + rowQ + g * 8);
  qf[1] = *(const bf16x8*)(qkv + rowQ + 32 + g * 8);

  f32x4 O[4] = {};
  f32x4 mrun, lrun;
#pragma unroll
  for (int r = 0; r < 4; ++r) { mrun[r] = -1e30f; lrun[r] = 0.f; }

  const float CSC = 0.125f * 1.44269504089f;
  const int nt = (qbase + 15) / 64 + 1;

  for (int t = w; t < nt; t += 4) {
    const int k0 = t * 64;
    f32x4 acc[4] = {};
    __builtin_amdgcn_s_setprio(1);
#pragma unroll
    for (int nf = 0; nf < 4; ++nf) {
      const long rowK = (long)(zb * TT + k0 + nf * 16 + c) * (3 * DD) + DD + zh * 64;
      bf16x8 kf0 = *(const bf16x8*)(qkv + rowK + g * 8);
      bf16x8 kf1 = *(const bf16x8*)(qkv + rowK + 32 + g * 8);
      acc[nf] = __builtin_amdgcn_mfma_f32_16x16x32_bf16(qf[0], kf0, acc[nf], 0, 0, 0);
      acc[nf] = __builtin_amdgcn_mfma_f32_16x16x32_bf16(qf[1], kf1, acc[nf], 0, 0, 0);
    }
    __builtin_amdgcn_s_setprio(0);
    f32x4 tv[4];
    const int mask_needed = (k0 + 63 > qbase);
#pragma unroll
    for (int nf = 0; nf < 4; ++nf) {
      const int k_abs = k0 + nf * 16 + c;
#pragma unroll
      for (int r = 0; r < 4; ++r) {
        float val = acc[nf][r] * CSC;
        if (mask_needed && k_abs > qbase + g * 4 + r) val = -1e30f;
        tv[nf][r] = val;
      }
    }
    f32x4 rmax;
#pragma unroll
    for (int r = 0; r < 4; ++r)
      rmax[r] = fmaxf(fmaxf(tv[0][r], tv[1][r]), fmaxf(tv[2][r], tv[3][r]));
#pragma unroll
    for (int off = 1; off < 16; off <<= 1) {
#pragma unroll
      for (int r = 0; r < 4; ++r) rmax[r] = fmaxf(rmax[r], __shfl_xor(rmax[r], off, 64));
    }
    f32x4 mnew, rfac;
#pragma unroll
    for (int r = 0; r < 4; ++r) {
      mnew[r] = fmaxf(mrun[r], rmax[r]);
      rfac[r] = exp2f(mrun[r] - mnew[r]);
      mrun[r] = mnew[r];
    }
    f32x4 e[4], rsum;
#pragma unroll
    for (int r = 0; r < 4; ++r) rsum[r] = 0.f;
#pragma unroll
    for (int nf = 0; nf < 4; ++nf)
#pragma unroll
      for (int r = 0; r < 4; ++r) {
        e[nf][r] = exp2f(tv[nf][r] - mnew[r]);
        rsum[r] += e[nf][r];
      }
#pragma unroll
    for (int off = 1; off < 16; off <<= 1) {
#pragma unroll
      for (int r = 0; r < 4; ++r) rsum[r] += __shfl_xor(rsum[r], off, 64);
    }
#pragma unroll
    for (int r = 0; r < 4; ++r) lrun[r] = lrun[r] * rfac[r] + rsum[r];
#pragma unroll
    for (int nf = 0; nf < 4; ++nf)
#pragma unroll
      for (int r = 0; r < 4; ++r) O[nf][r] *= rfac[r];
#pragma unroll
    for (int nf = 0; nf < 4; ++nf)
#pragma unroll
      for (int r = 0; r < 4; ++r)
        Pl[w][g * 4 + r][nf * 16 + c] = f2bf(e[nf][r]);
    asm volatile("s_waitcnt lgkmcnt(0)" ::: "memory");
    bf16x8 pf[2];
    pf[0] = *(const bf16x8*)&Pl[w][c][g * 8];
    pf[1] = *(const bf16x8*)&Pl[w][c][32 + g * 8];
    __builtin_amdgcn_s_setprio(1);
#pragma unroll
    for (int nf = 0; nf < 4; ++nf) {
      const long vrow = ((long)z * 64 + nf * 16 + c) * TT + k0;
      const bf16x8 vf0 = *(const bf16x8*)(vt + vrow + g * 8);
      const bf16x8 vf1 = *(const bf16x8*)(vt + vrow + 32 + g * 8);
      O[nf] = __builtin_amdgcn_mfma_f32_16x16x32_bf16(pf[0], vf0, O[nf], 0, 0, 0);
      O[nf] = __builtin_amdgcn_mfma_f32_16x16x32_bf16(pf[1], vf1, O[nf], 0, 0, 0);
    }
    __builtin_amdgcn_s_setprio(0);
  }

#pragma unroll
  for (int nf = 0; nf < 4; ++nf)
#pragma unroll
    for (int r = 0; r < 4; ++r)
      Ol[w][g * 4 + r][nf * 16 + c] = O[nf][r];
  if (c == 0) {
#pragma unroll
    for (int r = 0; r < 4; ++r) { ml[w][g * 4 + r] = mrun[r]; ll[w][g * 4 + r] = lrun[r]; }
  }
  __syncthreads();

  for (int e2 = threadIdx.x; e2 < 16 * 64; e2 += 256) {
    const int row = e2 >> 6, d = e2 & 63;
    const float M = fmaxf(fmaxf(ml[0][row], ml[1][row]), fmaxf(ml[2][row], ml[3][row]));
    float L = 0.f, Ov = 0.f;
#pragma unroll
    for (int u = 0; u < 4; ++u) {
      const float f = exp2f(ml[u][row] - M);
      L += ll[u][row] * f;
      Ov += Ol[u][row][d] * f;
    }
    y[(long)(zb * TT + qbase + row) * DD + zh * 64 + d] = f2bf(Ov / L);
  }
}

// ---------------- NT GEMM: C[m,n] = sum_k A[m,k] * B[n,k]  (+ epilogue) ----------------
// MFS=16: 16x16x32, separate A/B LDS tiles (conflict-free, layer GEMMs).
// MFS=32: 32x32x16 with INTERLEAVED A|B LDS rows (r13-verified LM config).
// PIPE=true -> 2-phase dbuf, counted vmcnt(GPT); PIPE=false -> single-buffer.
// EPI: 0 fp32*scale ; 1 bf16+bias ; 2 fp32 resid+acc+bias ; 3 bf16 gelu ;
//      5 qkv fused: Q/K -> bf16+bias; V -> bf16+bias transposed into vt (via resid arg)
template<int BM, int BN, int BK, int MFS, typename TB, int EPI, bool LMSWZ, bool PIPE>
__global__ __launch_bounds__(256) void gemm_nt(
    const short* __restrict__ A, const TB* __restrict__ Bm,
    const float* __restrict__ bias, const float* __restrict__ resid,
    void* __restrict__ Cout,
    int M, int N, int K, int lda, int ldb, int ldc,
    long aSB, long aSH, long bSB, long bSH, long cSB, long cSH,
    float scale, int causal)
{
  int n0, m0;
  if constexpr (LMSWZ) {
    const int l = blockIdx.x;
    const int x = l & 7;
    const int j = l >> 3;
    const int mt = j & 15;
    const int nl = j >> 4;
    const int npan = (N + BN - 1) / BN;
    const int q = npan >> 3, rr = npan & 7;
    const int cnt = q + (x < rr);
    if (nl >= cnt) return;
    const int nstart = x * q + (x < rr ? x : rr);
    n0 = (nstart + nl) * BN;
    m0 = mt * BM;
  } else {
    n0 = blockIdx.x * BN;
    m0 = blockIdx.y * BM;
  }
  if (causal && n0 >= m0 + BM) return;
  const int z = blockIdx.z;
  const int zb = z / HH, zh = z % HH;
  const short* Ag = A + zb * aSB + zh * aSH + (long)m0 * lda;
  const TB*    Bg = Bm + zb * bSB + zh * bSH;
  const long  cOff = zb * cSB + zh * cSH;

  constexpr int NBUF = PIPE ? 2 : 1;
  static_assert(MFS == 16 || (BM == BN && !PIPE), "ILV path needs BM==BN, single-buffer");
  __shared__ __align__(16) short LDSb[NBUF * (BM + BN) * BK];

  const int tid = threadIdx.x;
  const int lane = tid & 63, wid = tid >> 6;
  constexpr int WTM = BM / 2, WTN = BN / 2;
  constexpr int FM = WTM / 16, FN = WTN / 16;
  constexpr int FM2 = (MFS == 32) ? WTM / 32 : 1;
  constexpr int FN2 = (MFS == 32) ? WTN / 32 : 1;
  constexpr int AM = (MFS == 16) ? FM : FM2;
  constexpr int AN = (MFS == 16) ? FN : FN2;
  const int wr = wid >> 1, wc = wid & 1;

  using accT = typename std::conditional<MFS == 16, f32x4, f32x16>::type;
  accT acc[AM][AN] = {};

  constexpr bool B_IS_F32 = (sizeof(TB) == 4);
  constexpr int CPR = BK / 8;
  constexpr int NCA = BM * CPR;
  constexpr int NCB = BN * CPR;
  constexpr int IA = NCA / 256, IB = NCB / 256;
  constexpr int GPT = IA + IB;
  static_assert(CPR == 8, "swizzle assumes 128B operand rows (BK=64)");
  static_assert(B_IS_F32 || (NCA % 256 == 0 && NCB % 256 == 0), "chunk grid");

  auto aTile = [&](int buf) -> short* { return LDSb + buf * BM * BK; };
  auto bTile = [&](int buf) -> short* { return LDSb + NBUF * BM * BK + buf * BN * BK; };

  auto compute = [&](int buf) {
    if constexpr (MFS == 16) {
      const int kAoff = (lane >> 4) * 8;
      short* Als = aTile(buf);
      short* Bls = bTile(buf);
#pragma unroll
      for (int kk = 0; kk < BK; kk += 32) {
        bf16x8 af[AM], bfr[AN];
#pragma unroll
        for (int mi = 0; mi < AM; ++mi) {
          const int Ra = wr * WTM + mi * 16 + (lane & 15);
          const int kca = (kk + kAoff) >> 3;
          af[mi] = *(const bf16x8*)&Als[Ra * BK + ((kca ^ (Ra & 7)) << 3)];
        }
#pragma unroll
        for (int ni = 0; ni < AN; ++ni) {
          const int Rb = wc * WTN + ni * 16 + (lane & 15);
          const int kcb = (kk + kAoff) >> 3;
          bfr[ni] = *(const bf16x8*)&Bls[Rb * BK + ((kcb ^ (Rb & 7)) << 3)];
        }
#pragma unroll
        for (int mi = 0; mi < AM; ++mi)
#pragma unroll
          for (int ni = 0; ni < AN; ++ni)
            acc[mi][ni] = __builtin_amdgcn_mfma_f32_16x16x32_bf16(af[mi], bfr[ni], acc[mi][ni], 0, 0, 0);
      }
    } else {
#pragma unroll
      for (int kk = 0; kk < BK; kk += 16) {
        const int kc = (kk >> 3) + (lane >> 5);
        bf16x8 af[AM], bfr[AN];
#pragma unroll
        for (int mi = 0; mi < AM; ++mi) {
          const int Ra = wr * WTM + mi * 32 + (lane & 31);
          af[mi] = *(const bf16x8*)&LDSb[Ra * (2 * BK) + ((kc ^ (Ra & 15)) << 3)];
        }
#pragma unroll
        for (int ni = 0; ni < AN; ++ni) {
          const int Rb = wc * WTN + ni * 32 + (lane & 31);
          bfr[ni] = *(const bf16x8*)&LDSb[Rb * (2 * BK) + (((8 + kc) ^ (Rb & 15)) << 3)];
        }
#pragma unroll
        for (int mi = 0; mi < AM; ++mi)
#pragma unroll
          for (int ni = 0; ni < AN; ++ni)
            acc[mi][ni] = __builtin_amdgcn_mfma_f32_32x32x16_bf16(af[mi], bfr[ni], acc[mi][ni], 0, 0, 0);
      }
    }
  };

  if constexpr (!B_IS_F32) {
    const int ldsoff = wid * 64 * 16;
    if constexpr (MFS == 32) {
      constexpr int IT = BM * 16 / 256;
      const short* abp[IT];
#pragma unroll
      for (int i = 0; i < IT; ++i) {
        const int cc = i * 256 + tid;
        const int r = cc >> 4, cl = cc & 15;
        const int co = cl ^ (r & 15);
        if (co < 8) {
          abp[i] = Ag + (long)r * lda + co * 8;
        } else {
          int gr = n0 + r; gr = (gr < N) ? gr : (N - 1);
          abp[i] = (const short*)Bg + (long)gr * ldb + (co - 8) * 8;
        }
      }
      const int KT = K / BK;
      for (int kt = 0; kt < KT; ++kt) {
#pragma unroll
        for (int i = 0; i < IT; ++i) {
          gload16(abp[i], (char*)LDSb + i * 4096 + ldsoff);
          abp[i] += BK;
        }
        __syncthreads();
        compute(0);
        __syncthreads();
      }
    } else {
      const short* ap[IA];
      const short* bp[IB];
#pragma unroll
      for (int i = 0; i < IA; ++i) {
        const int cch = i * 256 + tid;
        const int r = cch / CPR, kc = cch % CPR;
        ap[i] = Ag + (long)r * lda + ((kc ^ (r & 7)) << 3);
      }
#pragma unroll
      for (int i = 0; i < IB; ++i) {
        const int cch = i * 256 + tid;
        const int r = cch / CPR, kc = cch % CPR;
        int gr = n0 + r; gr = (gr < N) ? gr : (N - 1);
        bp[i] = (const short*)Bg + (long)gr * ldb + ((kc ^ (r & 7)) << 3);
      }

      auto stage = [&](int buf) {
#pragma unroll
        for (int i = 0; i < IA; ++i) {
          gload16(ap[i], (char*)aTile(buf) + i * 4096 + ldsoff);
          ap[i] += BK;
        }
#pragma unroll
        for (int i = 0; i < IB; ++i) {
          gload16(bp[i], (char*)bTile(buf) + i * 4096 + ldsoff);
          bp[i] += BK;
        }
      };

      if constexpr (PIPE) {
        const int KT = K / BK;
        stage(0);
        for (int kt = 0; kt < KT; ++kt) {
          const int cur = kt & 1;
          if (kt + 1 < KT) {
            stage(cur ^ 1);
            asm volatile("s_waitcnt vmcnt(%0)" :: "i"(GPT));
          } else {
            asm volatile("s_waitcnt vmcnt(0)");
          }
          __builtin_amdgcn_sched_barrier(0);
          __builtin_amdgcn_s_barrier();
          __builtin_amdgcn_sched_barrier(0);
          compute(cur);
          asm volatile("" ::: "memory");
          __builtin_amdgcn_s_barrier();
          __builtin_amdgcn_sched_barrier(0);
        }
      } else {
        const int KT = K / BK;
        for (int kt = 0; kt < KT; ++kt) {
          stage(0);
          __syncthreads();
          compute(0);
          __syncthreads();
        }
      }
    }
  } else {
    for (int k0 = 0; k0 < K; k0 += BK) {
      if constexpr (MFS == 32) {
#pragma unroll
        for (int cc = tid; cc < BM * CPR; cc += 256) {
          int r = cc / CPR, kc = cc % CPR;
          const uint4 v = *(const uint4*)(Ag + (long)r * lda + k0 + kc * 8);
          *(uint4*)&LDSb[r * (2 * BK) + ((kc ^ (r & 15)) << 3)] = v;
        }
#pragma unroll
        for (int cc = tid; cc < BN * (BK / 4); cc += 256) {
          int r = cc / (BK / 4), kc4 = cc % (BK / 4);
          int gr = n0 + r; gr = (gr < N) ? gr : (N - 1);
          const float4 v = *(const float4*)((const float*)Bg + (long)gr * ldb + k0 + kc4 * 4);
          short4 h4;
          h4.x = f2bf(v.x); h4.y = f2bf(v.y); h4.z = f2bf(v.z); h4.w = f2bf(v.w);
          const int co = 8 + (kc4 >> 1);
          *(short4*)&LDSb[r * (2 * BK) + ((co ^ (r & 15)) << 3) + (kc4 & 1) * 4] = h4;
        }
      } else {
        short* Als = aTile(0);
        short* Bls = bTile(0);
#pragma unroll
        for (int cc = tid; cc < BM * CPR; cc += 256) {
          int r = cc / CPR, kc = cc % CPR;
          const uint4 v = *(const uint4*)(Ag + (long)r * lda + k0 + kc * 8);
          *(uint4*)&Als[r * BK + ((kc ^ (r & 7)) << 3)] = v;
        }
#pragma unroll
        for (int cc = tid; cc < BN * (BK / 4); cc += 256) {
          int r = cc / (BK / 4), kc4 = cc % (BK / 4);
          int gr = n0 + r; gr = (gr < N) ? gr : (N - 1);
          const float4 v = *(const float4*)((const float*)Bg + (long)gr * ldb + k0 + kc4 * 4);
          short4 h4;
          h4.x = f2bf(v.x); h4.y = f2bf(v.y); h4.z = f2bf(v.z); h4.w = f2bf(v.w);
          const int co = kc4 >> 1;
          *(short4*)&Bls[r * BK + ((co ^ (r & 7)) << 3) + (kc4 & 1) * 4] = h4;
        }
      }
      __syncthreads();
      compute(0);
      __syncthreads();
    }
  }

  // ---- epilogue ----
  if constexpr (MFS == 16) {
    const int rq = (lane >> 4) << 2;
    const int cl = lane & 15;
#pragma unroll
    for (int mi = 0; mi < AM; ++mi) {
#pragma unroll
      for (int ni = 0; ni < AN; ++ni) {
        const int cg = n0 + wc * WTN + ni * 16 + cl;
        if (cg >= N) continue;
        const int rbase = m0 + wr * WTM + mi * 16 + rq;
        if constexpr (EPI == 5) {
          if (cg >= 2 * DD) {
            const int hh = (cg - 2 * DD) >> 6, dd2 = (cg - 2 * DD) & 63;
            const int bI = rbase >> 10, tI = rbase & (TT - 1);
            const float bv = bias[cg];
            short4 h4;
            h4.x = f2bf(acc[mi][ni][0] + bv);
            h4.y = f2bf(acc[mi][ni][1] + bv);
            h4.z = f2bf(acc[mi][ni][2] + bv);
            h4.w = f2bf(acc[mi][ni][3] + bv);
            short* vtp = (short*)(void*)resid;
            *(short4*)(vtp + (((long)(bI * HH + hh) * 64 + dd2) << 10) + tI) = h4;
          } else {
#pragma unroll
            for (int q = 0; q < 4; ++q)
              ((short*)Cout)[(long)(rbase + q) * ldc + cg] = f2bf(acc[mi][ni][q] + bias[cg]);
          }
          continue;
        }
#pragma unroll
        for (int q = 0; q < 4; ++q) {
          const long cidx = cOff + (long)(rbase + q) * ldc + cg;
          const float v = acc[mi][ni][q];
          if constexpr (EPI == 0) {
            ((float*)Cout)[cidx] = v * scale;
          } else if constexpr (EPI == 1) {
            ((short*)Cout)[cidx] = f2bf(v + bias[cg]);
          } else if constexpr (EPI == 2) {
            ((float*)Cout)[cidx] = resid[cidx] + v + bias[cg];
          } else if constexpr (EPI == 3) {
            const float zz = v + bias[cg];
            ((short*)Cout)[cidx] = f2bf(0.5f * zz * (1.f + erff(zz * 0.70710678118f)));
          } else {
            ((short*)Cout)[cidx] = f2bf(v);
          }
        }
      }
    }
  } else {
    const int cl = lane & 31;
    const int rhi = (lane >> 5) * 4;
#pragma unroll
    for (int mi = 0; mi < AM; ++mi) {
#pragma unroll
      for (int ni = 0; ni < AN; ++ni) {
        const int cg = n0 + wc * WTN + ni * 32 + cl;
        if (cg >= N) continue;
#pragma unroll
        for (int reg = 0; reg < 16; ++reg) {
          const int row = m0 + wr * WTM + mi * 32 + (reg & 3) + ((reg >> 2) * 8) + rhi;
          const long cidx = cOff + (long)row * ldc + cg;
          const float v = acc[mi][ni][reg];
          if constexpr (EPI == 0) {
            ((float*)Cout)[cidx] = v * scale;
          } else if constexpr (EPI == 1) {
            ((short*)Cout)[cidx] = f2bf(v + bias[cg]);
          } else if constexpr (EPI == 2) {
            ((float*)Cout)[cidx] = resid[cidx] + v + bias[cg];
          } else if constexpr (EPI == 3) {
            const float zz = v + bias[cg];
            ((short*)Cout)[cidx] = f2bf(0.5f * zz * (1.f + erff(zz * 0.70710678118f)));
          } else {
            ((short*)Cout)[cidx] = f2bf(v);
          }
        }
      }
    }
  }
}

// ---------------- model driver ----------------
template<typename TB>
static void run_model(const int* idx, const float* tok_f, const float* pos,
                      const TB* wqkv, const float* bqkv, const TB* wproj, const float* bproj,
                      const float* ln1g, const float* ln1b, const float* ln2g, const float* ln2b,
                      const TB* w1, const float* b1, const TB* w2, const float* b2,
                      const float* lnfg, const float* lnfb, const TB* tok_w,
                      float* xa, float* xb, short* hbf, short* qkv, short* vt,
                      short* ybf, short* ffb,
                      float* out, hipStream_t stream)
{
  embed_k<<<dim3(MROWS * DD / 256), 256, 0, stream>>>(idx, tok_f, pos, xa);

  float* xc = xa;
  float* xn = xb;
  for (int l = 0; l < LL; ++l) {
    ln_k<<<dim3(MROWS / 4), 256, 0, stream>>>(xc, ln1g + l * DD, ln1b + l * DD, hbf);
    gemm_nt<128, 64, 64, 16, TB, 5, false, true><<<dim3(36, 16, 1), 256, 0, stream>>>(
        hbf, wqkv + (long)l * 3 * DD * DD, bqkv + l * 3 * DD, (const float*)vt, qkv,
        MROWS, 3 * DD, DD, DD, DD, 3 * DD, 0, 0, 0, 0, 0, 0, 1.f, 0);
    flash_k<<<dim3(64, 24), 256, 0, stream>>>(qkv, vt, ybf);
    gemm_nt<64, 64, 64, 16, TB, 2, false, true><<<dim3(12, 32, 1), 256, 0, stream>>>(
        ybf, wproj + (long)l * DD * DD, bproj + l * DD, xc, xn,
        MROWS, DD, DD, DD, DD, DD, 0, 0, 0, 0, 0, 0, 1.f, 0);
    ln_k<<<dim3(MROWS / 4), 256, 0, stream>>>(xn, ln2g + l * DD, ln2b + l * DD, hbf);
    gemm_nt<128, 64, 64, 16, TB, 3, false, true><<<dim3(48, 16, 1), 256, 0, stream>>>(
        hbf, w1 + (long)l * 4 * DD * DD, b1 + l * 4 * DD, nullptr, ffb,
        MROWS, 4 * DD, DD, DD, DD, 4 * DD, 0, 0, 0, 0, 0, 0, 1.f, 0);
    gemm_nt<64, 64, 64, 16, TB, 2, false, true><<<dim3(12, 32, 1), 256, 0, stream>>>(
        ffb, w2 + (long)l * DD * 4 * DD, b2 + l * DD, xn, xc,
        MROWS, DD, 4 * DD, 4 * DD, 4 * DD, DD, 0, 0, 0, 0, 0, 0, 1.f, 0);
  }
  ln_k<<<dim3(MROWS / 4), 256, 0, stream>>>(xc, lnfg, lnfb, hbf);
  // LM head: r13-verified 128^2 32x32 interleaved single-buffer
  gemm_nt<128, 128, 64, 32, TB, 0, true, false><<<dim3(6400, 1, 1), 256, 0, stream>>>(
      hbf, tok_w, nullptr, nullptr, out,
      MROWS, VV, DD, DD, DD, VV, 0, 0, 0, 0, 0, 0, 1.f, 0);
}

extern "C" void kernel_launch(void* const* d_in, const int* in_sizes, int n_in,
                              void* d_out, int out_size, void* d_ws, size_t ws_size,
                              hipStream_t stream)
{
  const int*   idx  = (const int*)d_in[0];
  const float* tok  = (const float*)d_in[1];
  const float* pos  = (const float*)d_in[2];
  const float* wqkv = (const float*)d_in[3];
  const float* bqkv = (const float*)d_in[4];
  const float* wproj= (const float*)d_in[5];
  const float* bproj= (const float*)d_in[6];
  const float* ln1g = (const float*)d_in[7];
  const float* ln1b = (const float*)d_in[8];
  const float* ln2g = (const float*)d_in[9];
  const float* ln2b = (const float*)d_in[10];
  const float* w1   = (const float*)d_in[11];
  const float* b1   = (const float*)d_in[12];
  const float* w2   = (const float*)d_in[13];
  const float* b2   = (const float*)d_in[14];
  const float* lnfg = (const float*)d_in[15];
  const float* lnfb = (const float*)d_in[16];
  float* out = (float*)d_out;

  const long E_WQKV = (long)LL * 3 * DD * DD;
  const long E_WPRJ = (long)LL * DD * DD;
  const long E_W1   = (long)LL * 4 * DD * DD;
  const long E_W2   = E_W1;
  const long E_TOK  = (long)VV * DD;
  const long E_WSUM = E_WQKV + E_WPRJ + E_W1 + E_W2 + E_TOK;

  const size_t NEED_B = 44040192;
  const size_t NEED_A = NEED_B + 2 * (size_t)E_WSUM;

  if (ws_size < NEED_B) return;
  const bool bf16w = (ws_size >= NEED_A);

  char* ws = (char*)d_ws;
  short *wqkv_h = nullptr, *wprj_h = nullptr, *w1_h = nullptr, *w2_h = nullptr, *tok_h = nullptr;
  if (bf16w) {
    wqkv_h = (short*)ws; ws += E_WQKV * 2;
    wprj_h = (short*)ws; ws += E_WPRJ * 2;
    w1_h   = (short*)ws; ws += E_W1 * 2;
    w2_h   = (short*)ws; ws += E_W2 * 2;
    tok_h  = (short*)ws; ws += E_TOK * 2;
  }
  float* xa  = (float*)ws; ws += (size_t)MROWS * DD * 4;
  float* xb  = (float*)ws; ws += (size_t)MROWS * DD * 4;
  short* hbf = (short*)ws; ws += (size_t)MROWS * DD * 2;
  short* qkv = (short*)ws; ws += (size_t)MROWS * 3 * DD * 2;
  short* vt  = (short*)ws; ws += (size_t)24 * 64 * TT * 2;
  short* ybf = (short*)ws; ws += (size_t)MROWS * DD * 2;
  short* ffb = (short*)ws; ws += (size_t)MROWS * 4 * DD * 2;

  if (bf16w) {
    CvtArgs ca;
    ca.s[0] = wqkv; ca.d[0] = wqkv_h; ca.n4[0] = E_WQKV / 4;
    ca.s[1] = wproj; ca.d[1] = wprj_h; ca.n4[1] = E_WPRJ / 4;
    ca.s[2] = w1;   ca.d[2] = w1_h;   ca.n4[2] = E_W1 / 4;
    ca.s[3] = w2;   ca.d[3] = w2_h;   ca.n4[3] = E_W2 / 4;
    ca.s[4] = tok;  ca.d[4] = tok_h;  ca.n4[4] = E_TOK / 4;
    const long tot = (E_WQKV + E_WPRJ + E_W1 + E_W2 + E_TOK) / 4;
    cvt5_k<<<dim3(4096), 256, 0, stream>>>(ca, tot);
    run_model<short>(idx, tok, pos, wqkv_h, bqkv, wprj_h, bproj,
                     ln1g, ln1b, ln2g, ln2b, w1_h, b1, w2_h, b2, lnfg, lnfb, tok_h,
                     xa, xb, hbf, qkv, vt, ybf, ffb, out, stream);
  } else {
    run_model<float>(idx, tok, pos, wqkv, bqkv, wproj, bproj,
                     ln1g, ln1b, ln2g, ln2b, w1, b1, w2, b2, lnfg, lnfb, tok,
                     xa, xb, hbf, qkv, vt, ybf, ffb, out, stream);
  }
}

// Round 19
// 2018.194 us; speedup vs baseline: 1.0323x; 1.0071x over previous
//
#include <hip/hip_runtime.h>
#include <hip/hip_bf16.h>
#include <type_traits>

#define TT 1024
#define DD 768
#define HH 12
#define LL 12
#define VV 50257
#define MROWS 2048   // B*T

typedef __attribute__((ext_vector_type(4))) float f32x4;
typedef __attribute__((ext_vector_type(16))) float f32x16;
typedef __attribute__((ext_vector_type(8))) short bf16x8;

__device__ __forceinline__ short f2bf(float f) {
  __hip_bfloat16 h = __float2bfloat16(f);
  short s;
  __builtin_memcpy(&s, &h, 2);
  return s;
}

__device__ __forceinline__ void gload16(const void* g, void* l) {
  __builtin_amdgcn_global_load_lds(
      (const __attribute__((address_space(1))) unsigned int*)g,
      (__attribute__((address_space(3))) unsigned int*)l, 16, 0, 0);
}

__device__ __forceinline__ float wsum(float v) {
#pragma unroll
  for (int o = 32; o; o >>= 1) v += __shfl_xor(v, o, 64);
  return v;
}

// ---------------- fp32 -> bf16 weight conversion, 5 tensors in one launch ----------------
struct CvtArgs { const float* s[5]; short* d[5]; long n4[5]; };

__global__ __launch_bounds__(256) void cvt5_k(CvtArgs a, long tot)
{
  const long stride = (long)gridDim.x * 256;
  for (long i = (long)blockIdx.x * 256 + threadIdx.x; i < tot; i += stride) {
    long off = i;
    int s = 0;
#pragma unroll
    for (int q = 0; q < 4; ++q) {
      if (off >= a.n4[s]) { off -= a.n4[s]; ++s; }
    }
    const float4 v = ((const float4*)a.s[s])[off];
    short4 h;
    h.x = f2bf(v.x); h.y = f2bf(v.y); h.z = f2bf(v.z); h.w = f2bf(v.w);
    ((short4*)a.d[s])[off] = h;
  }
}

// ---------------- embedding ----------------
__global__ __launch_bounds__(256) void embed_k(const int* __restrict__ idx,
    const float* __restrict__ tok, const float* __restrict__ pos,
    float* __restrict__ x)
{
  int i = blockIdx.x * 256 + threadIdx.x;
  int d = i % DD;
  int bt = i / DD;
  int t = bt & (TT - 1);
  x[i] = tok[(long)idx[bt] * DD + d] + pos[t * DD + d];
}

// ---------------- LayerNorm: 1 wave per row, 4 rows per block ----------------
__global__ __launch_bounds__(256) void ln_k(const float* __restrict__ x,
    const float* __restrict__ g, const float* __restrict__ b,
    short* __restrict__ out)
{
  const int w = threadIdx.x >> 6;
  const int lane = threadIdx.x & 63;
  const int row = blockIdx.x * 4 + w;
  const float* xr = x + (long)row * DD;
  float4 v[3];
  float s = 0.f, s2 = 0.f;
#pragma unroll
  for (int i = 0; i < 3; ++i) {
    v[i] = ((const float4*)xr)[lane + i * 64];
    s  += v[i].x + v[i].y + v[i].z + v[i].w;
    s2 += v[i].x * v[i].x + v[i].y * v[i].y + v[i].z * v[i].z + v[i].w * v[i].w;
  }
  s = wsum(s); s2 = wsum(s2);
  const float mu = s * (1.f / DD);
  const float var = s2 * (1.f / DD) - mu * mu;
  const float rstd = rsqrtf(var + 1e-5f);
#pragma unroll
  for (int i = 0; i < 3; ++i) {
    const int d0 = (lane + i * 64) * 4;
    short4 h;
    h.x = f2bf((v[i].x - mu) * rstd * g[d0 + 0] + b[d0 + 0]);
    h.y = f2bf((v[i].y - mu) * rstd * g[d0 + 1] + b[d0 + 1]);
    h.z = f2bf((v[i].z - mu) * rstd * g[d0 + 2] + b[d0 + 2]);
    h.w = f2bf((v[i].w - mu) * rstd * g[d0 + 3] + b[d0 + 3]);
    ((short4*)(out + (long)row * DD))[lane + i * 64] = h;
  }
}

// ---------------- flash attention, 4-way kv-split, KVBLK=64 ----------------
__global__ __launch_bounds__(256) void flash_k(const short* __restrict__ qkv,
                                               const short* __restrict__ vt,
                                               short* __restrict__ y)
{
  const int qt = (int)gridDim.x - 1 - (int)blockIdx.x;  // longest blocks first
  const int z  = blockIdx.y;
  const int zb = z / HH, zh = z % HH;
  const int w    = threadIdx.x >> 6;
  const int lane = threadIdx.x & 63;
  const int c = lane & 15, g = lane >> 4;

  __shared__ __align__(16) short Pl[4][16][72];
  __shared__ float Ol[4][16][64];
  __shared__ float ml[4][16], ll[4][16];

  const int qbase = qt * 16;
  const long rowQ = (long)(zb * TT + qbase + c) * (3 * DD) + zh * 64;

  bf16x8 qf[2];
  qf[0] = *(const bf16x8*)(qkv + rowQ + g * 8);
  qf[1] = *(const bf16x8*)(qkv + rowQ + 32 + g * 8);

  f32x4 O[4] = {};
  f32x4 mrun, lrun;
#pragma unroll
  for (int r = 0; r < 4; ++r) { mrun[r] = -1e30f; lrun[r] = 0.f; }

  const float CSC = 0.125f * 1.44269504089f;
  const int nt = (qbase + 15) / 64 + 1;

  for (int t = w; t < nt; t += 4) {
    const int k0 = t * 64;
    f32x4 acc[4] = {};
#pragma unroll
    for (int nf = 0; nf < 4; ++nf) {
      const long rowK = (long)(zb * TT + k0 + nf * 16 + c) * (3 * DD) + DD + zh * 64;
      bf16x8 kf0 = *(const bf16x8*)(qkv + rowK + g * 8);
      bf16x8 kf1 = *(const bf16x8*)(qkv + rowK + 32 + g * 8);
      acc[nf] = __builtin_amdgcn_mfma_f32_16x16x32_bf16(qf[0], kf0, acc[nf], 0, 0, 0);
      acc[nf] = __builtin_amdgcn_mfma_f32_16x16x32_bf16(qf[1], kf1, acc[nf], 0, 0, 0);
    }
    f32x4 tv[4];
    const int mask_needed = (k0 + 63 > qbase);
#pragma unroll
    for (int nf = 0; nf < 4; ++nf) {
      const int k_abs = k0 + nf * 16 + c;
#pragma unroll
      for (int r = 0; r < 4; ++r) {
        float val = acc[nf][r] * CSC;
        if (mask_needed && k_abs > qbase + g * 4 + r) val = -1e30f;
        tv[nf][r] = val;
      }
    }
    f32x4 rmax;
#pragma unroll
    for (int r = 0; r < 4; ++r)
      rmax[r] = fmaxf(fmaxf(tv[0][r], tv[1][r]), fmaxf(tv[2][r], tv[3][r]));
#pragma unroll
    for (int off = 1; off < 16; off <<= 1) {
#pragma unroll
      for (int r = 0; r < 4; ++r) rmax[r] = fmaxf(rmax[r], __shfl_xor(rmax[r], off, 64));
    }
    f32x4 mnew, rfac;
#pragma unroll
    for (int r = 0; r < 4; ++r) {
      mnew[r] = fmaxf(mrun[r], rmax[r]);
      rfac[r] = exp2f(mrun[r] - mnew[r]);
      mrun[r] = mnew[r];
    }
    f32x4 e[4], rsum;
#pragma unroll
    for (int r = 0; r < 4; ++r) rsum[r] = 0.f;
#pragma unroll
    for (int nf = 0; nf < 4; ++nf)
#pragma unroll
      for (int r = 0; r < 4; ++r) {
        e[nf][r] = exp2f(tv[nf][r] - mnew[r]);
        rsum[r] += e[nf][r];
      }
#pragma unroll
    for (int off = 1; off < 16; off <<= 1) {
#pragma unroll
      for (int r = 0; r < 4; ++r) rsum[r] += __shfl_xor(rsum[r], off, 64);
    }
#pragma unroll
    for (int r = 0; r < 4; ++r) lrun[r] = lrun[r] * rfac[r] + rsum[r];
#pragma unroll
    for (int nf = 0; nf < 4; ++nf)
#pragma unroll
      for (int r = 0; r < 4; ++r) O[nf][r] *= rfac[r];
#pragma unroll
    for (int nf = 0; nf < 4; ++nf)
#pragma unroll
      for (int r = 0; r < 4; ++r)
        Pl[w][g * 4 + r][nf * 16 + c] = f2bf(e[nf][r]);
    asm volatile("s_waitcnt lgkmcnt(0)" ::: "memory");
    bf16x8 pf[2];
    pf[0] = *(const bf16x8*)&Pl[w][c][g * 8];
    pf[1] = *(const bf16x8*)&Pl[w][c][32 + g * 8];
#pragma unroll
    for (int nf = 0; nf < 4; ++nf) {
      const long vrow = ((long)z * 64 + nf * 16 + c) * TT + k0;
      const bf16x8 vf0 = *(const bf16x8*)(vt + vrow + g * 8);
      const bf16x8 vf1 = *(const bf16x8*)(vt + vrow + 32 + g * 8);
      O[nf] = __builtin_amdgcn_mfma_f32_16x16x32_bf16(pf[0], vf0, O[nf], 0, 0, 0);
      O[nf] = __builtin_amdgcn_mfma_f32_16x16x32_bf16(pf[1], vf1, O[nf], 0, 0, 0);
    }
  }

#pragma unroll
  for (int nf = 0; nf < 4; ++nf)
#pragma unroll
    for (int r = 0; r < 4; ++r)
      Ol[w][g * 4 + r][nf * 16 + c] = O[nf][r];
  if (c == 0) {
#pragma unroll
    for (int r = 0; r < 4; ++r) { ml[w][g * 4 + r] = mrun[r]; ll[w][g * 4 + r] = lrun[r]; }
  }
  __syncthreads();

  for (int e2 = threadIdx.x; e2 < 16 * 64; e2 += 256) {
    const int row = e2 >> 6, d = e2 & 63;
    const float M = fmaxf(fmaxf(ml[0][row], ml[1][row]), fmaxf(ml[2][row], ml[3][row]));
    float L = 0.f, Ov = 0.f;
#pragma unroll
    for (int u = 0; u < 4; ++u) {
      const float f = exp2f(ml[u][row] - M);
      L += ll[u][row] * f;
      Ov += Ol[u][row][d] * f;
    }
    y[(long)(zb * TT + qbase + row) * DD + zh * 64 + d] = f2bf(Ov / L);
  }
}

// ---------------- NT GEMM: C[m,n] = sum_k A[m,k] * B[n,k]  (+ epilogue) ----------------
// MFS=16: 16x16x32, separate A/B LDS tiles (conflict-free, layer GEMMs).
// MFS=32: 32x32x16 with INTERLEAVED A|B LDS rows (256B rows, 16 chunks, XOR by
//         r&15) — conflict-free 32-row fragment reads (r13-verified LM config).
// PIPE=true -> 2-phase dbuf, counted vmcnt(GPT); PIPE=false -> single-buffer.
// EPI: 0 fp32*scale ; 1 bf16+bias ; 2 fp32 resid+acc+bias ; 3 bf16 gelu ;
//      5 qkv fused: Q/K -> bf16+bias; V -> bf16+bias transposed into vt (via resid arg)
template<int BM, int BN, int BK, int MFS, typename TB, int EPI, bool LMSWZ, bool PIPE>
__global__ __launch_bounds__(256) void gemm_nt(
    const short* __restrict__ A, const TB* __restrict__ Bm,
    const float* __restrict__ bias, const float* __restrict__ resid,
    void* __restrict__ Cout,
    int M, int N, int K, int lda, int ldb, int ldc,
    long aSB, long aSH, long bSB, long bSH, long cSB, long cSH,
    float scale, int causal)
{
  int n0, m0;
  if constexpr (LMSWZ) {
    const int l = blockIdx.x;
    const int x = l & 7;
    const int j = l >> 3;
    const int mt = j & 15;
    const int nl = j >> 4;
    const int npan = (N + BN - 1) / BN;
    const int q = npan >> 3, rr = npan & 7;
    const int cnt = q + (x < rr);
    if (nl >= cnt) return;
    const int nstart = x * q + (x < rr ? x : rr);
    n0 = (nstart + nl) * BN;
    m0 = mt * BM;
  } else {
    n0 = blockIdx.x * BN;
    m0 = blockIdx.y * BM;
  }
  if (causal && n0 >= m0 + BM) return;
  const int z = blockIdx.z;
  const int zb = z / HH, zh = z % HH;
  const short* Ag = A + zb * aSB + zh * aSH + (long)m0 * lda;
  const TB*    Bg = Bm + zb * bSB + zh * bSH;
  const long  cOff = zb * cSB + zh * cSH;

  constexpr int NBUF = PIPE ? 2 : 1;
  static_assert(MFS == 16 || (BM == BN && !PIPE), "ILV path needs BM==BN, single-buffer");
  __shared__ __align__(16) short LDSb[NBUF * (BM + BN) * BK];

  const int tid = threadIdx.x;
  const int lane = tid & 63, wid = tid >> 6;
  constexpr int WTM = BM / 2, WTN = BN / 2;
  constexpr int FM = WTM / 16, FN = WTN / 16;
  constexpr int FM2 = (MFS == 32) ? WTM / 32 : 1;
  constexpr int FN2 = (MFS == 32) ? WTN / 32 : 1;
  constexpr int AM = (MFS == 16) ? FM : FM2;
  constexpr int AN = (MFS == 16) ? FN : FN2;
  const int wr = wid >> 1, wc = wid & 1;

  using accT = typename std::conditional<MFS == 16, f32x4, f32x16>::type;
  accT acc[AM][AN] = {};

  constexpr bool B_IS_F32 = (sizeof(TB) == 4);
  constexpr int CPR = BK / 8;            // 16B chunks per row (per operand)
  constexpr int NCA = BM * CPR;
  constexpr int NCB = BN * CPR;
  constexpr int IA = NCA / 256, IB = NCB / 256;
  constexpr int GPT = IA + IB;           // gloads per thread per tile
  static_assert(CPR == 8, "swizzle assumes 128B operand rows (BK=64)");
  static_assert(B_IS_F32 || (NCA % 256 == 0 && NCB % 256 == 0), "chunk grid");

  auto aTile = [&](int buf) -> short* { return LDSb + buf * BM * BK; };
  auto bTile = [&](int buf) -> short* { return LDSb + NBUF * BM * BK + buf * BN * BK; };

  auto compute = [&](int buf) {
    if constexpr (MFS == 16) {
      const int kAoff = (lane >> 4) * 8;
      short* Als = aTile(buf);
      short* Bls = bTile(buf);
#pragma unroll
      for (int kk = 0; kk < BK; kk += 32) {
        bf16x8 af[AM], bfr[AN];
#pragma unroll
        for (int mi = 0; mi < AM; ++mi) {
          const int Ra = wr * WTM + mi * 16 + (lane & 15);
          const int kca = (kk + kAoff) >> 3;
          af[mi] = *(const bf16x8*)&Als[Ra * BK + ((kca ^ (Ra & 7)) << 3)];
        }
#pragma unroll
        for (int ni = 0; ni < AN; ++ni) {
          const int Rb = wc * WTN + ni * 16 + (lane & 15);
          const int kcb = (kk + kAoff) >> 3;
          bfr[ni] = *(const bf16x8*)&Bls[Rb * BK + ((kcb ^ (Rb & 7)) << 3)];
        }
#pragma unroll
        for (int mi = 0; mi < AM; ++mi)
#pragma unroll
          for (int ni = 0; ni < AN; ++ni)
            acc[mi][ni] = __builtin_amdgcn_mfma_f32_16x16x32_bf16(af[mi], bfr[ni], acc[mi][ni], 0, 0, 0);
      }
    } else {
      // interleaved rows: row r = [A chunks 0..7 | B chunks 8..15], swizzle ^ (r&15)
#pragma unroll
      for (int kk = 0; kk < BK; kk += 16) {
        const int kc = (kk >> 3) + (lane >> 5);   // operand chunk 0..7
        bf16x8 af[AM], bfr[AN];
#pragma unroll
        for (int mi = 0; mi < AM; ++mi) {
          const int Ra = wr * WTM + mi * 32 + (lane & 31);
          af[mi] = *(const bf16x8*)&LDSb[Ra * (2 * BK) + ((kc ^ (Ra & 15)) << 3)];
        }
#pragma unroll
        for (int ni = 0; ni < AN; ++ni) {
          const int Rb = wc * WTN + ni * 32 + (lane & 31);
          bfr[ni] = *(const bf16x8*)&LDSb[Rb * (2 * BK) + (((8 + kc) ^ (Rb & 15)) << 3)];
        }
#pragma unroll
        for (int mi = 0; mi < AM; ++mi)
#pragma unroll
          for (int ni = 0; ni < AN; ++ni)
            acc[mi][ni] = __builtin_amdgcn_mfma_f32_32x32x16_bf16(af[mi], bfr[ni], acc[mi][ni], 0, 0, 0);
      }
    }
  };

  if constexpr (!B_IS_F32) {
    const int ldsoff = wid * 64 * 16;    // wave-uniform base; HW adds lane*16
    if constexpr (MFS == 32) {
      // ---- interleaved staging: per-lane source decodes A-or-B from orig chunk ----
      constexpr int IT = BM * 16 / 256;  // staging gloads per thread
      const short* abp[IT];
#pragma unroll
      for (int i = 0; i < IT; ++i) {
        const int cc = i * 256 + tid;
        const int r = cc >> 4, cl = cc & 15;
        const int co = cl ^ (r & 15);
        if (co < 8) {
          abp[i] = Ag + (long)r * lda + co * 8;
        } else {
          int gr = n0 + r; gr = (gr < N) ? gr : (N - 1);
          abp[i] = (const short*)Bg + (long)gr * ldb + (co - 8) * 8;
        }
      }
      const int KT = K / BK;
      for (int kt = 0; kt < KT; ++kt) {
#pragma unroll
        for (int i = 0; i < IT; ++i) {
          gload16(abp[i], (char*)LDSb + i * 4096 + ldsoff);
          abp[i] += BK;
        }
        __syncthreads();
        compute(0);
        __syncthreads();
      }
    } else {
      const short* ap[IA];
      const short* bp[IB];
#pragma unroll
      for (int i = 0; i < IA; ++i) {
        const int cch = i * 256 + tid;
        const int r = cch / CPR, kc = cch % CPR;
        ap[i] = Ag + (long)r * lda + ((kc ^ (r & 7)) << 3);
      }
#pragma unroll
      for (int i = 0; i < IB; ++i) {
        const int cch = i * 256 + tid;
        const int r = cch / CPR, kc = cch % CPR;
        int gr = n0 + r; gr = (gr < N) ? gr : (N - 1);
        bp[i] = (const short*)Bg + (long)gr * ldb + ((kc ^ (r & 7)) << 3);
      }

      auto stage = [&](int buf) {
#pragma unroll
        for (int i = 0; i < IA; ++i) {
          gload16(ap[i], (char*)aTile(buf) + i * 4096 + ldsoff);
          ap[i] += BK;
        }
#pragma unroll
        for (int i = 0; i < IB; ++i) {
          gload16(bp[i], (char*)bTile(buf) + i * 4096 + ldsoff);
          bp[i] += BK;
        }
      };

      if constexpr (PIPE) {
        const int KT = K / BK;
        stage(0);
        for (int kt = 0; kt < KT; ++kt) {
          const int cur = kt & 1;
          if (kt + 1 < KT) {
            stage(cur ^ 1);
            asm volatile("s_waitcnt vmcnt(%0)" :: "i"(GPT));
          } else {
            asm volatile("s_waitcnt vmcnt(0)");
          }
          __builtin_amdgcn_sched_barrier(0);
          __builtin_amdgcn_s_barrier();
          __builtin_amdgcn_sched_barrier(0);
          compute(cur);
          asm volatile("" ::: "memory");
          __builtin_amdgcn_s_barrier();
          __builtin_amdgcn_sched_barrier(0);
        }
      } else {
        const int KT = K / BK;
        for (int kt = 0; kt < KT; ++kt) {
          stage(0);
          __syncthreads();
          compute(0);
          __syncthreads();
        }
      }
    }
  } else {
    // --- fp32 fallback: synchronous single-buffer staging with on-the-fly cvt ---
    for (int k0 = 0; k0 < K; k0 += BK) {
      if constexpr (MFS == 32) {
#pragma unroll
        for (int cc = tid; cc < BM * CPR; cc += 256) {
          int r = cc / CPR, kc = cc % CPR;
          const uint4 v = *(const uint4*)(Ag + (long)r * lda + k0 + kc * 8);
          *(uint4*)&LDSb[r * (2 * BK) + ((kc ^ (r & 15)) << 3)] = v;
        }
#pragma unroll
        for (int cc = tid; cc < BN * (BK / 4); cc += 256) {
          int r = cc / (BK / 4), kc4 = cc % (BK / 4);
          int gr = n0 + r; gr = (gr < N) ? gr : (N - 1);
          const float4 v = *(const float4*)((const float*)Bg + (long)gr * ldb + k0 + kc4 * 4);
          short4 h4;
          h4.x = f2bf(v.x); h4.y = f2bf(v.y); h4.z = f2bf(v.z); h4.w = f2bf(v.w);
          const int co = 8 + (kc4 >> 1);
          *(short4*)&LDSb[r * (2 * BK) + ((co ^ (r & 15)) << 3) + (kc4 & 1) * 4] = h4;
        }
      } else {
        short* Als = aTile(0);
        short* Bls = bTile(0);
#pragma unroll
        for (int cc = tid; cc < BM * CPR; cc += 256) {
          int r = cc / CPR, kc = cc % CPR;
          const uint4 v = *(const uint4*)(Ag + (long)r * lda + k0 + kc * 8);
          *(uint4*)&Als[r * BK + ((kc ^ (r & 7)) << 3)] = v;
        }
#pragma unroll
        for (int cc = tid; cc < BN * (BK / 4); cc += 256) {
          int r = cc / (BK / 4), kc4 = cc % (BK / 4);
          int gr = n0 + r; gr = (gr < N) ? gr : (N - 1);
          const float4 v = *(const float4*)((const float*)Bg + (long)gr * ldb + k0 + kc4 * 4);
          short4 h4;
          h4.x = f2bf(v.x); h4.y = f2bf(v.y); h4.z = f2bf(v.z); h4.w = f2bf(v.w);
          const int co = kc4 >> 1;
          *(short4*)&Bls[r * BK + ((co ^ (r & 7)) << 3) + (kc4 & 1) * 4] = h4;
        }
      }
      __syncthreads();
      compute(0);
      __syncthreads();
    }
  }

  // ---- epilogue ----
  if constexpr (MFS == 16) {
    const int rq = (lane >> 4) << 2;
    const int cl = lane & 15;
#pragma unroll
    for (int mi = 0; mi < AM; ++mi) {
#pragma unroll
      for (int ni = 0; ni < AN; ++ni) {
        const int cg = n0 + wc * WTN + ni * 16 + cl;
        if (cg >= N) continue;
        const int rbase = m0 + wr * WTM + mi * 16 + rq;
        if constexpr (EPI == 5) {
          if (cg >= 2 * DD) {
            const int hh = (cg - 2 * DD) >> 6, dd2 = (cg - 2 * DD) & 63;
            const int bI = rbase >> 10, tI = rbase & (TT - 1);
            const float bv = bias[cg];
            short4 h4;
            h4.x = f2bf(acc[mi][ni][0] + bv);
            h4.y = f2bf(acc[mi][ni][1] + bv);
            h4.z = f2bf(acc[mi][ni][2] + bv);
            h4.w = f2bf(acc[mi][ni][3] + bv);
            short* vtp = (short*)(void*)resid;
            *(short4*)(vtp + (((long)(bI * HH + hh) * 64 + dd2) << 10) + tI) = h4;
          } else {
#pragma unroll
            for (int q = 0; q < 4; ++q)
              ((short*)Cout)[(long)(rbase + q) * ldc + cg] = f2bf(acc[mi][ni][q] + bias[cg]);
          }
          continue;
        }
#pragma unroll
        for (int q = 0; q < 4; ++q) {
          const long cidx = cOff + (long)(rbase + q) * ldc + cg;
          const float v = acc[mi][ni][q];
          if constexpr (EPI == 0) {
            ((float*)Cout)[cidx] = v * scale;
          } else if constexpr (EPI == 1) {
            ((short*)Cout)[cidx] = f2bf(v + bias[cg]);
          } else if constexpr (EPI == 2) {
            ((float*)Cout)[cidx] = resid[cidx] + v + bias[cg];
          } else if constexpr (EPI == 3) {
            const float zz = v + bias[cg];
            ((short*)Cout)[cidx] = f2bf(0.5f * zz * (1.f + erff(zz * 0.70710678118f)));
          } else {
            ((short*)Cout)[cidx] = f2bf(v);
          }
        }
      }
    }
  } else {
    const int cl = lane & 31;
    const int rhi = (lane >> 5) * 4;
#pragma unroll
    for (int mi = 0; mi < AM; ++mi) {
#pragma unroll
      for (int ni = 0; ni < AN; ++ni) {
        const int cg = n0 + wc * WTN + ni * 32 + cl;
        if (cg >= N) continue;
#pragma unroll
        for (int reg = 0; reg < 16; ++reg) {
          const int row = m0 + wr * WTM + mi * 32 + (reg & 3) + ((reg >> 2) * 8) + rhi;
          const long cidx = cOff + (long)row * ldc + cg;
          const float v = acc[mi][ni][reg];
          if constexpr (EPI == 0) {
            ((float*)Cout)[cidx] = v * scale;
          } else if constexpr (EPI == 1) {
            ((short*)Cout)[cidx] = f2bf(v + bias[cg]);
          } else if constexpr (EPI == 2) {
            ((float*)Cout)[cidx] = resid[cidx] + v + bias[cg];
          } else if constexpr (EPI == 3) {
            const float zz = v + bias[cg];
            ((short*)Cout)[cidx] = f2bf(0.5f * zz * (1.f + erff(zz * 0.70710678118f)));
          } else {
            ((short*)Cout)[cidx] = f2bf(v);
          }
        }
      }
    }
  }
}

// ---------------- model driver ----------------
template<typename TB>
static void run_model(const int* idx, const float* tok_f, const float* pos,
                      const TB* wqkv, const float* bqkv, const TB* wproj, const float* bproj,
                      const float* ln1g, const float* ln1b, const float* ln2g, const float* ln2b,
                      const TB* w1, const float* b1, const TB* w2, const float* b2,
                      const float* lnfg, const float* lnfb, const TB* tok_w,
                      float* xa, float* xb, short* hbf, short* qkv, short* vt,
                      short* ybf, short* ffb,
                      float* out, hipStream_t stream)
{
  embed_k<<<dim3(MROWS * DD / 256), 256, 0, stream>>>(idx, tok_f, pos, xa);

  float* xc = xa;
  float* xn = xb;
  for (int l = 0; l < LL; ++l) {
    ln_k<<<dim3(MROWS / 4), 256, 0, stream>>>(xc, ln1g + l * DD, ln1b + l * DD, hbf);
    gemm_nt<128, 64, 64, 16, TB, 5, false, true><<<dim3(36, 16, 1), 256, 0, stream>>>(
        hbf, wqkv + (long)l * 3 * DD * DD, bqkv + l * 3 * DD, (const float*)vt, qkv,
        MROWS, 3 * DD, DD, DD, DD, 3 * DD, 0, 0, 0, 0, 0, 0, 1.f, 0);
    flash_k<<<dim3(64, 24), 256, 0, stream>>>(qkv, vt, ybf);
    gemm_nt<64, 64, 64, 16, TB, 2, false, true><<<dim3(12, 32, 1), 256, 0, stream>>>(
        ybf, wproj + (long)l * DD * DD, bproj + l * DD, xc, xn,
        MROWS, DD, DD, DD, DD, DD, 0, 0, 0, 0, 0, 0, 1.f, 0);
    ln_k<<<dim3(MROWS / 4), 256, 0, stream>>>(xn, ln2g + l * DD, ln2b + l * DD, hbf);
    gemm_nt<128, 64, 64, 16, TB, 3, false, true><<<dim3(48, 16, 1), 256, 0, stream>>>(
        hbf, w1 + (long)l * 4 * DD * DD, b1 + l * 4 * DD, nullptr, ffb,
        MROWS, 4 * DD, DD, DD, DD, 4 * DD, 0, 0, 0, 0, 0, 0, 1.f, 0);
    gemm_nt<64, 64, 64, 16, TB, 2, false, true><<<dim3(12, 32, 1), 256, 0, stream>>>(
        ffb, w2 + (long)l * DD * 4 * DD, b2 + l * DD, xn, xc,
        MROWS, DD, 4 * DD, 4 * DD, 4 * DD, DD, 0, 0, 0, 0, 0, 0, 1.f, 0);
  }
  ln_k<<<dim3(MROWS / 4), 256, 0, stream>>>(xc, lnfg, lnfb, hbf);
  // LM head: 32x32 MFMA + interleaved A|B swizzle (conflict-free), single-buffer
  gemm_nt<128, 128, 64, 32, TB, 0, true, false><<<dim3(6400, 1, 1), 256, 0, stream>>>(
      hbf, tok_w, nullptr, nullptr, out,
      MROWS, VV, DD, DD, DD, VV, 0, 0, 0, 0, 0, 0, 1.f, 0);
}

extern "C" void kernel_launch(void* const* d_in, const int* in_sizes, int n_in,
                              void* d_out, int out_size, void* d_ws, size_t ws_size,
                              hipStream_t stream)
{
  const int*   idx  = (const int*)d_in[0];
  const float* tok  = (const float*)d_in[1];
  const float* pos  = (const float*)d_in[2];
  const float* wqkv = (const float*)d_in[3];
  const float* bqkv = (const float*)d_in[4];
  const float* wproj= (const float*)d_in[5];
  const float* bproj= (const float*)d_in[6];
  const float* ln1g = (const float*)d_in[7];
  const float* ln1b = (const float*)d_in[8];
  const float* ln2g = (const float*)d_in[9];
  const float* ln2b = (const float*)d_in[10];
  const float* w1   = (const float*)d_in[11];
  const float* b1   = (const float*)d_in[12];
  const float* w2   = (const float*)d_in[13];
  const float* b2   = (const float*)d_in[14];
  const float* lnfg = (const float*)d_in[15];
  const float* lnfb = (const float*)d_in[16];
  float* out = (float*)d_out;

  const long E_WQKV = (long)LL * 3 * DD * DD;
  const long E_WPRJ = (long)LL * DD * DD;
  const long E_W1   = (long)LL * 4 * DD * DD;
  const long E_W2   = E_W1;
  const long E_TOK  = (long)VV * DD;
  const long E_WSUM = E_WQKV + E_WPRJ + E_W1 + E_W2 + E_TOK;

  const size_t NEED_B = 44040192;
  const size_t NEED_A = NEED_B + 2 * (size_t)E_WSUM;

  if (ws_size < NEED_B) return;
  const bool bf16w = (ws_size >= NEED_A);

  char* ws = (char*)d_ws;
  short *wqkv_h = nullptr, *wprj_h = nullptr, *w1_h = nullptr, *w2_h = nullptr, *tok_h = nullptr;
  if (bf16w) {
    wqkv_h = (short*)ws; ws += E_WQKV * 2;
    wprj_h = (short*)ws; ws += E_WPRJ * 2;
    w1_h   = (short*)ws; ws += E_W1 * 2;
    w2_h   = (short*)ws; ws += E_W2 * 2;
    tok_h  = (short*)ws; ws += E_TOK * 2;
  }
  float* xa  = (float*)ws; ws += (size_t)MROWS * DD * 4;
  float* xb  = (float*)ws; ws += (size_t)MROWS * DD * 4;
  short* hbf = (short*)ws; ws += (size_t)MROWS * DD * 2;
  short* qkv = (short*)ws; ws += (size_t)MROWS * 3 * DD * 2;
  short* vt  = (short*)ws; ws += (size_t)24 * 64 * TT * 2;
  short* ybf = (short*)ws; ws += (size_t)MROWS * DD * 2;
  short* ffb = (short*)ws; ws += (size_t)MROWS * 4 * DD * 2;

  if (bf16w) {
    CvtArgs ca;
    ca.s[0] = wqkv; ca.d[0] = wqkv_h; ca.n4[0] = E_WQKV / 4;
    ca.s[1] = wproj; ca.d[1] = wprj_h; ca.n4[1] = E_WPRJ / 4;
    ca.s[2] = w1;   ca.d[2] = w1_h;   ca.n4[2] = E_W1 / 4;
    ca.s[3] = w2;   ca.d[3] = w2_h;   ca.n4[3] = E_W2 / 4;
    ca.s[4] = tok;  ca.d[4] = tok_h;  ca.n4[4] = E_TOK / 4;
    const long tot = (E_WQKV + E_WPRJ + E_W1 + E_W2 + E_TOK) / 4;
    cvt5_k<<<dim3(4096), 256, 0, stream>>>(ca, tot);
    run_model<short>(idx, tok, pos, wqkv_h, bqkv, wprj_h, bproj,
                     ln1g, ln1b, ln2g, ln2b, w1_h, b1, w2_h, b2, lnfg, lnfb, tok_h,
                     xa, xb, hbf, qkv, vt, ybf, ffb, out, stream);
  } else {
    run_model<float>(idx, tok, pos, wqkv, bqkv, wproj, bproj,
                     ln1g, ln1b, ln2g, ln2b, w1, b1, w2, b2, lnfg, lnfb, tok,
                     xa, xb, hbf, qkv, vt, ybf, ffb, out, stream);
  }
}